// Round 7
// baseline (2621.094 us; speedup 1.0000x reference)
//
#include <hip/hip_runtime.h>

// ---------------------------------------------------------------------------
// OGRENet GraphNet block — f16 MFMA with BLOCKED operand layout.
// Blocked layout (f16): offset(m,k) = ((mt*KT + kt)*4 + kg)*1024 + r*8 + ko
//   mt=m>>7, r=m&127, kt=k>>5, kg=(k>>3)&3, ko=k&7.   (tile = 128x32 = 8KB)
// Staging reads are 1KB-contiguous per global_load_lds; frag reads conflict-free.
// Epilogue mode 0 re-blocks C via 2-pass LDS transpose (16.9KB LDS);
// mode 1 = f32 row-major. Scatter-mean via separate coalesced atomic kernel.
// XCD swizzle: 8 column-blocks of one M-panel land on the same XCD.
// ---------------------------------------------------------------------------

#define NN 20000
#define EE 100000
#define BB 16

typedef _Float16 f16x8 __attribute__((ext_vector_type(8)));
typedef _Float16 f16x4 __attribute__((ext_vector_type(4)));
typedef float f32x4 __attribute__((ext_vector_type(4)));

__device__ __forceinline__ int clampi(int v, int hi) {
    return v < 0 ? 0 : (v >= hi ? hi - 1 : v);
}

__device__ __forceinline__ void gld_lds16(const void* g, void* l) {
    __builtin_amdgcn_global_load_lds(
        (const __attribute__((address_space(1))) unsigned int*)g,
        (__attribute__((address_space(3))) unsigned int*)l, 16, 0, 0);
}

// ------------------------- blocked f16 MFMA GEMM ---------------------------
__global__ __launch_bounds__(256) void gemm_blk(
    const _Float16* __restrict__ A,      // blocked [MT][KT]
    const _Float16* __restrict__ Wt,     // blocked [NT][KT]
    int KT,
    const float* __restrict__ bias, int ldbias, const int* __restrict__ gbid,
    void* __restrict__ C, int KTo, int ktOff,   // mode 0: blocked f16 out
    int ldc,                                    // mode 1: f32 row-major out
    int M, int relu, int mode)
{
    __shared__ char smem[16896];                 // max(16KB staging, 64*132*2)
    _Float16* As = (_Float16*)smem;              // 4096 f16
    _Float16* Bs = As + 4096;

    const int tid  = threadIdx.x;
    const int lane = tid & 63;
    const int wid  = tid >> 6;
    const int wm = (wid & 1) << 6;
    const int wn = (wid >> 1) << 6;

    // XCD swizzle: panel p's column-blocks share f%8 (same XCD)
    const int nb = gridDim.x;
    const int MT = gridDim.y;
    int f = blockIdx.y * nb + blockIdx.x;
    const int MT8 = MT & ~7;
    int p, c;
    if (f < MT8 * nb) {
        c = (f >> 3) % nb;
        p = (f & 7) + 8 * ((f >> 3) / nb);
    } else {
        int g = f - MT8 * nb;
        p = MT8 + g / nb;
        c = g % nb;
    }

    f32x4 acc[4][4];
#pragma unroll
    for (int i = 0; i < 4; ++i)
#pragma unroll
        for (int j = 0; j < 4; ++j) acc[i][j] = (f32x4){0.f, 0.f, 0.f, 0.f};

    const _Float16* pA = A + (size_t)p * KT * 4096;
    const _Float16* pB = Wt + (size_t)c * KT * 4096;
    const int cb0 = wid * 64;         // chunk base, inst 0
    const int cb1 = 256 + wid * 64;   // chunk base, inst 1
    const int kq  = (lane >> 4) * 128;
    const int l15 = lane & 15;
    const int l4  = (lane >> 4) << 2;

    for (int kt = 0; kt < KT; ++kt) {
        __syncthreads();
        gld_lds16(pA + (size_t)(cb0 + lane) * 8, As + cb0 * 8);
        gld_lds16(pA + (size_t)(cb1 + lane) * 8, As + cb1 * 8);
        gld_lds16(pB + (size_t)(cb0 + lane) * 8, Bs + cb0 * 8);
        gld_lds16(pB + (size_t)(cb1 + lane) * 8, Bs + cb1 * 8);
        pA += 4096; pB += 4096;
        __syncthreads();

        f16x8 af[4], bf[4];
#pragma unroll
        for (int i = 0; i < 4; ++i)
            af[i] = *(const f16x8*)(As + (size_t)((kq + wm + i * 16 + l15) << 3));
#pragma unroll
        for (int j = 0; j < 4; ++j)
            bf[j] = *(const f16x8*)(Bs + (size_t)((kq + wn + j * 16 + l15) << 3));
#pragma unroll
        for (int i = 0; i < 4; ++i)
#pragma unroll
            for (int j = 0; j < 4; ++j)
                acc[i][j] = __builtin_amdgcn_mfma_f32_16x16x32_f16(af[i], bf[j], acc[i][j], 0, 0, 0);
    }

    if (mode == 0) {
        // re-block C through LDS, two passes of 64 rows (tr = [64][132] f16)
        _Float16* tr = (_Float16*)smem;
#pragma unroll
        for (int pass = 0; pass < 2; ++pass) {
            __syncthreads();
            if (wm == pass * 64) {      // waves holding rows [pass*64, pass*64+64)
#pragma unroll
                for (int i = 0; i < 4; ++i) {
#pragma unroll
                    for (int v = 0; v < 4; ++v) {
                        const int lr = i * 16 + l4 + v;          // local row 0..63
                        const float* brow = bias;
                        if (gbid) {
                            int m = p * 128 + pass * 64 + lr;
                            if (m >= M) m = M - 1;
                            brow = bias + (size_t)clampi(gbid[m], BB) * ldbias;
                        }
#pragma unroll
                        for (int j = 0; j < 4; ++j) {
                            const int cc = wn + j * 16 + l15;
                            float val = acc[i][j][v] + brow[c * 128 + cc];
                            if (relu) val = fmaxf(val, 0.f);
                            tr[lr * 132 + cc] = (_Float16)val;
                        }
                    }
                }
            }
            __syncthreads();
#pragma unroll
            for (int it = 0; it < 4; ++it) {
                const int id = it * 256 + tid;   // 0..1023
                const int r  = id & 63;          // local row
                const int cg = id >> 6;          // 0..15
                f16x4 lo = *(const f16x4*)(tr + r * 132 + cg * 8);
                f16x4 hi = *(const f16x4*)(tr + r * 132 + cg * 8 + 4);
                f16x8 v8;
#pragma unroll
                for (int t = 0; t < 4; ++t) { v8[t] = lo[t]; v8[t + 4] = hi[t]; }
                const int kti = ktOff + (c << 2) + (cg >> 2);
                const int gr  = pass * 64 + r;
                size_t o = (((size_t)p * KTo + kti) * 4 + (cg & 3)) * 1024 + (size_t)gr * 8;
                *(f16x8*)((_Float16*)C + o) = v8;
            }
        }
    } else {
#pragma unroll
        for (int i = 0; i < 4; ++i) {
#pragma unroll
            for (int v = 0; v < 4; ++v) {
                const int m = p * 128 + wm + i * 16 + l4 + v;
                if (m >= M) continue;
                const float* brow = bias;
                if (gbid) brow = bias + (size_t)clampi(gbid[m], BB) * ldbias;
#pragma unroll
                for (int j = 0; j < 4; ++j) {
                    const int col = c * 128 + wn + j * 16 + l15;
                    float val = acc[i][j][v] + brow[col];
                    if (relu) val = fmaxf(val, 0.f);
                    ((float*)C)[(size_t)m * ldc + col] = val;
                }
            }
        }
    }
}

// ------------------------- helper kernels ----------------------------------

// fp32 w[N][Ksrc] -> blocked f16 [N/128][Kd/32] tiles.
// colmap mode: 0 plain (k<Ksrc), 1 e0 (k<19), 2 pack544 (k<9 | 32<=k<544 -> 9+(k-32))
__global__ void k_w2h_blk(const float* __restrict__ src, _Float16* __restrict__ dst,
                          int N, int Ksrc, int Kd, int mode)
{
    int t = blockIdx.x * blockDim.x + threadIdx.x;
    if (t >= N * Kd) return;
    int n = t / Kd, k = t - n * Kd;
    int sc = -1;
    if (mode == 0)      { if (k < Ksrc) sc = k; }
    else if (mode == 1) { if (k < 19) sc = k; }
    else                { if (k < 9) sc = k; else if (k >= 32 && k < 544) sc = 9 + (k - 32); }
    float v = (sc >= 0) ? src[(size_t)n * Ksrc + sc] : 0.f;
    int KT = Kd >> 5;
    int nt = n >> 7, r = n & 127, kt = k >> 5, kg = (k >> 3) & 3, ko = k & 7;
    dst[(((size_t)nt * KT + kt) * 4 + kg) * 1024 + (size_t)r * 8 + ko] = (_Float16)v;
}

// u_r[16,256] fp32
__global__ void k_u_r(const float* __restrict__ u, const float* __restrict__ w_sel,
                      const float* __restrict__ b_sel, float* __restrict__ u_r)
{
    int wave = (blockIdx.x * 256 + threadIdx.x) >> 6;
    int lane = threadIdx.x & 63;
    int b = wave >> 8, n = wave & 255;
    const float4* u4 = (const float4*)(u + (size_t)b * 4096);
    const float4* w4 = (const float4*)(w_sel + (size_t)n * 4096);
    float s = 0.f;
    for (int i = lane; i < 1024; i += 64) {
        float4 a = u4[i], c = w4[i];
        s += a.x * c.x + a.y * c.y + a.z * c.z + a.w * c.w;
    }
    for (int off = 32; off; off >>= 1) s += __shfl_down(s, off);
    if (lane == 0) u_r[b * 256 + n] = s + b_sel[n];
}

// ub[16][Nout] = u_r @ w[:, koff:koff+256]^T + b
__global__ void k_graph_bias(const float* __restrict__ u_r, const float* __restrict__ w,
                             const float* __restrict__ b, float* __restrict__ ub,
                             int Nout, int Ksrc, int koff)
{
    int wave = (blockIdx.x * 256 + threadIdx.x) >> 6;
    int lane = threadIdx.x & 63;
    if (wave >= 16 * Nout) return;
    int g = wave / Nout, n = wave - g * Nout;
    const float* ur = u_r + (size_t)g * 256;
    const float* wr = w + (size_t)n * Ksrc + koff;
    float s = 0.f;
#pragma unroll
    for (int i = 0; i < 4; ++i) s += ur[lane * 4 + i] * wr[lane * 4 + i];
    for (int off = 32; off; off >>= 1) s += __shfl_down(s, off);
    if (lane == 0) ub[(size_t)g * Nout + n] = s + b[n];
}

__global__ void k_gbe(const int* __restrict__ row, const int* __restrict__ batch,
                      int* __restrict__ gbe)
{
    int e = blockIdx.x * blockDim.x + threadIdx.x;
    if (e < EE) gbe[e] = clampi(batch[clampi(row[e], NN)], BB);
}

// e_in blocked [MT][1]: cols = [x[row](9) | x[col](9) | ea | 0..]
__global__ void k_gather_edge_blk(const float* __restrict__ x, const float* __restrict__ ea,
                                  const int* __restrict__ row, const int* __restrict__ col,
                                  _Float16* __restrict__ dst, int e0, int ec, int MTR)
{
    int t = blockIdx.x * blockDim.x + threadIdx.x;
    if (t >= MTR * 4) return;
    int r = t >> 2, kg = t & 3;
    int e = e0 + r; int emax = e0 + ec - 1;
    if (e > emax) e = emax;
    int ri = clampi(row[e], NN), ci = clampi(col[e], NN);
    f16x8 v;
#pragma unroll
    for (int j = 0; j < 8; ++j) {
        int cc = kg * 8 + j;
        float fv = 0.f;
        if (cc < 9)       fv = x[(size_t)ri * 9 + cc];
        else if (cc < 18) fv = x[(size_t)ci * 9 + (cc - 9)];
        else if (cc == 18) fv = ea[e];
        v[j] = (_Float16)fv;
    }
    *(f16x8*)(dst + (size_t)(r >> 7) * 4096 + (size_t)kg * 1024 + (size_t)(r & 127) * 8) = v;
}

// ninb kt0 (x[col] | pad) blocked; kt1..16 written by ew4's epilogue
__global__ void k_gather_nin0(const float* __restrict__ x, const int* __restrict__ col,
                              _Float16* __restrict__ dst, int e0, int ec, int MTR)
{
    int t = blockIdx.x * blockDim.x + threadIdx.x;
    if (t >= MTR * 4) return;
    int r = t >> 2, kg = t & 3;
    int e = e0 + r; int emax = e0 + ec - 1;
    if (e > emax) e = emax;
    int ci = clampi(col[e], NN);
    f16x8 v = (f16x8)(_Float16)0.f;
#pragma unroll
    for (int j = 0; j < 8; ++j) {
        int cc = kg * 8 + j;
        if (cc < 9) v[j] = (_Float16)x[(size_t)ci * 9 + cc];
    }
    *(f16x8*)(dst + ((size_t)(r >> 7) * 17) * 4096 + (size_t)kg * 1024 + (size_t)(r & 127) * 8) = v;
}

// m_in blocked [MTm][17]: cols = [x(9)|pad23 | agg/cnt(512)]
__global__ void k_gather_min(const float* __restrict__ x, const float* __restrict__ agg,
                             const float* __restrict__ cnt, _Float16* __restrict__ dst, int MTR)
{
    int t = blockIdx.x * blockDim.x + threadIdx.x;
    if (t >= MTR * 68) return;
    int r = t / 68, q = t - r * 68;
    int kt = q >> 2, kg = q & 3;
    int n = r < NN ? r : NN - 1;
    f16x8 v = (f16x8)(_Float16)0.f;
    if (kt == 0) {
#pragma unroll
        for (int j = 0; j < 8; ++j) {
            int cc = kg * 8 + j;
            if (cc < 9) v[j] = (_Float16)x[(size_t)n * 9 + cc];
        }
    } else {
        float inv = 1.f / fmaxf(cnt[n], 1.f);
        int cbase = (kt - 1) * 32 + kg * 8;
        const float4* ap = (const float4*)(agg + (size_t)n * 512 + cbase);
        float4 a0 = ap[0], a1 = ap[1];
        v[0] = (_Float16)(a0.x * inv); v[1] = (_Float16)(a0.y * inv);
        v[2] = (_Float16)(a0.z * inv); v[3] = (_Float16)(a0.w * inv);
        v[4] = (_Float16)(a1.x * inv); v[5] = (_Float16)(a1.y * inv);
        v[6] = (_Float16)(a1.z * inv); v[7] = (_Float16)(a1.w * inv);
    }
    *(f16x8*)(dst + ((size_t)(r >> 7) * 17 + kt) * 4096 + (size_t)kg * 1024 + (size_t)(r & 127) * 8) = v;
}

__global__ void k_count(const int* __restrict__ row, float* __restrict__ cnt)
{
    int e = blockIdx.x * blockDim.x + threadIdx.x;
    if (e < EE) atomicAdd(&cnt[clampi(row[e], NN)], 1.f);
}

// coalesced scatter: one thread per (edge, col); wave covers 64 consecutive cols
__global__ void k_scatter_add(const float* __restrict__ nh2, const int* __restrict__ row,
                              float* __restrict__ agg, int e0, int ec)
{
    int t = blockIdx.x * blockDim.x + threadIdx.x;
    if (t >= ec * 512) return;
    int el = t >> 9, c = t & 511;
    int r = clampi(row[e0 + el], NN);
    atomicAdd(&agg[(size_t)r * 512 + c], nh2[(size_t)el * 512 + c]);
}

// out[n] = h2[n,:] . mw1 + mb1
__global__ void k_final(const float* __restrict__ h2, const float* __restrict__ mw1,
                        const float* __restrict__ mb1, float* __restrict__ out)
{
    int wave = (blockIdx.x * 256 + threadIdx.x) >> 6;
    int lane = threadIdx.x & 63;
    if (wave >= NN) return;
    const float4* h4 = (const float4*)(h2 + (size_t)wave * 512);
    const float4* w4 = (const float4*)mw1;
    float s = 0.f;
#pragma unroll
    for (int i = 0; i < 2; ++i) {
        int f = lane * 2 + i;
        float4 a = h4[f], b = w4[f];
        s += a.x * b.x + a.y * b.y + a.z * b.z + a.w * b.w;
    }
    for (int off = 32; off; off >>= 1) s += __shfl_down(s, off);
    if (lane == 0) out[wave] = s + mb1[0];
}

// ------------------------------- host --------------------------------------

#define GRID1(n) dim3(((n) + 255) / 256)

static inline void gemmB(hipStream_t s, const _Float16* A, const _Float16* Wt, int KT,
                         const float* bias, int ldbias, const int* gbid,
                         void* C, int KTo, int ktOff, int ldc,
                         int M, int MT, int NT, int relu, int mode)
{
    hipLaunchKernelGGL(gemm_blk, dim3(NT, MT), dim3(256), 0, s,
                       A, Wt, KT, bias, ldbias, gbid, C, KTo, ktOff, ldc,
                       M, relu, mode);
}

extern "C" void kernel_launch(void* const* d_in, const int* in_sizes, int n_in,
                              void* d_out, int out_size, void* d_ws, size_t ws_size,
                              hipStream_t stream)
{
    const float* x     = (const float*)d_in[0];
    const int*   ei    = (const int*)d_in[1];
    const float* ea    = (const float*)d_in[2];
    const float* u     = (const float*)d_in[3];
    const int*   batch = (const int*)d_in[4];
    const float* w_sel = (const float*)d_in[5];
    const float* b_sel = (const float*)d_in[6];
    const float* ew0 = (const float*)d_in[7];   const float* eb0 = (const float*)d_in[8];
    const float* ew1 = (const float*)d_in[9];   const float* eb1 = (const float*)d_in[10];
    const float* ew2 = (const float*)d_in[11];  const float* eb2 = (const float*)d_in[12];
    const float* ew3 = (const float*)d_in[13];  const float* eb3 = (const float*)d_in[14];
    const float* ew4 = (const float*)d_in[15];  const float* eb4 = (const float*)d_in[16];
    const float* nw0 = (const float*)d_in[17];  const float* nb0 = (const float*)d_in[18];
    const float* nw1 = (const float*)d_in[19];  const float* nb1 = (const float*)d_in[20];
    const float* mw0 = (const float*)d_in[21];  const float* mb0 = (const float*)d_in[22];
    const float* mw1 = (const float*)d_in[23];  const float* mb1 = (const float*)d_in[24];

    const int* row = ei;
    const int* col = ei + EE;

    char* W = (char*)d_ws;
    size_t off = 0;
    auto alloc = [&](size_t bytes) -> char* {
        char* p = W + off;
        off = (off + bytes + 255) & ~(size_t)255;
        return p;
    };
    float*    cnt  = (float*)alloc(20000 * 4);
    float*    agg  = (float*)alloc((size_t)NN * 512 * 4);
    const size_t zeroBytes = off;
    float*    u_r  = (float*)alloc(16 * 256 * 4);
    float*    ub0  = (float*)alloc(16 * 1024 * 4);
    float*    ubm  = (float*)alloc(16 * 512 * 4);
    int*      gbe  = (int*)alloc((size_t)EE * 4);
    _Float16* wh0  = (_Float16*)alloc((size_t)8 * 1 * 4096 * 2);
    _Float16* wh1  = (_Float16*)alloc((size_t)8 * 32 * 4096 * 2);
    _Float16* wh2  = (_Float16*)alloc((size_t)8 * 32 * 4096 * 2);
    _Float16* wh3  = (_Float16*)alloc((size_t)8 * 32 * 4096 * 2);
    _Float16* wh4  = (_Float16*)alloc((size_t)4 * 32 * 4096 * 2);
    _Float16* whn0 = (_Float16*)alloc((size_t)4 * 17 * 4096 * 2);
    _Float16* whn1 = (_Float16*)alloc((size_t)4 * 16 * 4096 * 2);
    _Float16* whm0 = (_Float16*)alloc((size_t)4 * 17 * 4096 * 2);
    const int MTm = (NN + 127) / 128;           // 157
    float*    h2   = (float*)alloc((size_t)NN * 512 * 4);
    _Float16* m_in = (_Float16*)alloc((size_t)MTm * 17 * 4096 * 2);
    const size_t fixedBytes = off;

    // choose edge chunk (depends only on ws_size -> capture-safe).
    // prefer 25000: chunk working set (~180MB) stays L3-resident.
    static const int ecOpts[] = {25000, 12500, 10000, 5000};
    int EC = 5000;
    for (int i = 0; i < 4; ++i) {
        int ec = ecOpts[i];
        size_t MTRc = (size_t)((ec + 127) / 128) * 128;
        size_t need = fixedBytes + MTRc * 32 * 2 + 2 * (MTRc * 1024 * 2)
                    + MTRc * 544 * 2 + MTRc * 512 * 4 + 4096;
        if (need <= ws_size) { EC = ec; break; }
    }
    const int MT  = (EC + 127) / 128;
    const size_t MTR = (size_t)MT * 128;
    _Float16* e_in = (_Float16*)alloc(MTR * 32 * 2);    // [MT][1]
    _Float16* ping = (_Float16*)alloc(MTR * 1024 * 2);  // [MT][32]
    _Float16* pong = (_Float16*)alloc(MTR * 1024 * 2);  // [MT][32]
    _Float16* ninb = (_Float16*)alloc(MTR * 544 * 2);   // [MT][17]
    float*    bufD = (float*)alloc(MTR * 512 * 4);      // nh2 f32 row-major
    const int NCH = (EE + EC - 1) / EC;

    (void)hipMemsetAsync(W, 0, zeroBytes, stream);

    hipLaunchKernelGGL(k_u_r, dim3(1024), dim3(256), 0, stream, u, w_sel, b_sel, u_r);
    hipLaunchKernelGGL(k_graph_bias, GRID1(16 * 1024 * 64), dim3(256), 0, stream,
                       u_r, ew0, eb0, ub0, 1024, 275, 19);
    hipLaunchKernelGGL(k_graph_bias, GRID1(16 * 512 * 64), dim3(256), 0, stream,
                       u_r, mw0, mb0, ubm, 512, 777, 521);
    hipLaunchKernelGGL(k_gbe, GRID1(EE), dim3(256), 0, stream, row, batch, gbe);

    auto pack = [&](const float* w, _Float16* wh, int N, int Ksrc, int Kd, int mode) {
        hipLaunchKernelGGL(k_w2h_blk, GRID1(N * Kd), dim3(256), 0, stream, w, wh, N, Ksrc, Kd, mode);
    };
    pack(ew0, wh0, 1024, 275, 32, 1);
    pack(ew1, wh1, 1024, 1024, 1024, 0);
    pack(ew2, wh2, 1024, 1024, 1024, 0);
    pack(ew3, wh3, 1024, 1024, 1024, 0);
    pack(ew4, wh4, 512, 1024, 1024, 0);
    pack(nw0, whn0, 512, 521, 544, 2);
    pack(nw1, whn1, 512, 512, 512, 0);
    pack(mw0, whm0, 512, 777, 544, 2);

    hipLaunchKernelGGL(k_count, GRID1(EE), dim3(256), 0, stream, row, cnt);

    for (int ch = 0; ch < NCH; ++ch) {
        int e0 = ch * EC;
        int ec = EC; if (e0 + ec > EE) ec = EE - e0;
        hipLaunchKernelGGL(k_gather_edge_blk, GRID1((int)MTR * 4), dim3(256), 0, stream,
                           x, ea, row, col, e_in, e0, ec, (int)MTR);
        // l0: K=32, per-graph bias ub0
        gemmB(stream, e_in, wh0, 1, ub0, 1024, gbe + e0, ping, 32, 0, 0,
              ec, MT, 8, 1, 0);
        gemmB(stream, ping, wh1, 32, eb1, 0, nullptr, pong, 32, 0, 0,
              ec, MT, 8, 1, 0);
        gemmB(stream, pong, wh2, 32, eb2, 0, nullptr, ping, 32, 0, 0,
              ec, MT, 8, 1, 0);
        gemmB(stream, ping, wh3, 32, eb3, 0, nullptr, pong, 32, 0, 0,
              ec, MT, 8, 1, 0);
        // ew4 -> ninb (blocked, kt offset 1), no relu on edge_out
        gemmB(stream, pong, wh4, 32, eb4, 0, nullptr, ninb, 17, 1, 0,
              ec, MT, 4, 0, 0);
        hipLaunchKernelGGL(k_gather_nin0, GRID1((int)MTR * 4), dim3(256), 0, stream,
                           x, col, ninb, e0, ec, (int)MTR);
        gemmB(stream, ninb, whn0, 17, nb0, 0, nullptr, ping, 16, 0, 0,
              ec, MT, 4, 1, 0);
        // n1: f32 row-major out, then coalesced scatter
        gemmB(stream, ping, whn1, 16, nb1, 0, nullptr, bufD, 0, 0, 512,
              ec, MT, 4, 1, 1);
        hipLaunchKernelGGL(k_scatter_add, GRID1(ec * 512), dim3(256), 0, stream,
                           bufD, row, agg, e0, ec);
    }

    hipLaunchKernelGGL(k_gather_min, GRID1((int)(MTm * 128) * 68), dim3(256), 0, stream,
                       x, agg, cnt, m_in, MTm * 128);
    // m0: f32 row-major out, per-graph bias ubm (gbid = batch)
    gemmB(stream, m_in, whm0, 17, ubm, 512, batch, h2, 0, 0, 512,
          NN, MTm, 4, 1, 1);
    hipLaunchKernelGGL(k_final, dim3((NN + 3) / 4), dim3(256), 0, stream,
                       h2, mw1, mb1, (float*)d_out);
}

// Round 8
// 2546.405 us; speedup vs baseline: 1.0293x; 1.0293x over previous
//
#include <hip/hip_runtime.h>

// ---------------------------------------------------------------------------
// OGRENet GraphNet block — f16 MFMA with BLOCKED operand layout.
// Blocked layout (f16): offset(m,k) = ((mt*KT + kt)*4 + kg)*1024 + r*8 + ko
//   mt=m>>7, r=m&127, kt=k>>5, kg=(k>>3)&3, ko=k&7.   (tile = 128x32 = 8KB)
// Staging reads are 1KB-contiguous per global_load_lds; frag reads conflict-free.
// Epilogue mode 0: re-block C via 2-pass LDS transpose (f16, conflict-free).
// mode 1: f32 row-major.  mode 2: fused scatter-mean add — 4-pass f32 LDS
// transpose (stride 130, <=2-way banks) then COALESCED atomics (wave = 64
// consecutive cols of one agg row).  [R7 lesson: rocprof serialized replay
// overstates atomic kernels ~20x; trust timed totals.]
// XCD swizzle: 8 column-blocks of one M-panel land on the same XCD.
// ---------------------------------------------------------------------------

#define NN 20000
#define EE 100000
#define BB 16

typedef _Float16 f16x8 __attribute__((ext_vector_type(8)));
typedef _Float16 f16x4 __attribute__((ext_vector_type(4)));
typedef float f32x4 __attribute__((ext_vector_type(4)));

__device__ __forceinline__ int clampi(int v, int hi) {
    return v < 0 ? 0 : (v >= hi ? hi - 1 : v);
}

__device__ __forceinline__ void gld_lds16(const void* g, void* l) {
    __builtin_amdgcn_global_load_lds(
        (const __attribute__((address_space(1))) unsigned int*)g,
        (__attribute__((address_space(3))) unsigned int*)l, 16, 0, 0);
}

// ------------------------- blocked f16 MFMA GEMM ---------------------------
__global__ __launch_bounds__(256) void gemm_blk(
    const _Float16* __restrict__ A,      // blocked [MT][KT]
    const _Float16* __restrict__ Wt,     // blocked [NT][KT]
    int KT,
    const float* __restrict__ bias, int ldbias, const int* __restrict__ gbid,
    void* __restrict__ C, int KTo, int ktOff,   // mode 0: blocked f16 out
    int ldc,                                    // mode 1: f32 row-major out
    const int* __restrict__ srow, float* __restrict__ agg,  // mode 2
    int M, int relu, int mode)
{
    __shared__ char smem[16896];   // staging 16384 | m0 tr 64*132*2 | m2 trf 32*130*4
    _Float16* As = (_Float16*)smem;
    _Float16* Bs = As + 4096;

    const int tid  = threadIdx.x;
    const int lane = tid & 63;
    const int wid  = tid >> 6;
    const int wm = (wid & 1) << 6;
    const int wn = (wid >> 1) << 6;

    // XCD swizzle: panel p's column-blocks share f%8 (same XCD)
    const int nb = gridDim.x;
    const int MT = gridDim.y;
    int f = blockIdx.y * nb + blockIdx.x;
    const int MT8 = MT & ~7;
    int p, c;
    if (f < MT8 * nb) {
        c = (f >> 3) % nb;
        p = (f & 7) + 8 * ((f >> 3) / nb);
    } else {
        int g = f - MT8 * nb;
        p = MT8 + g / nb;
        c = g % nb;
    }

    f32x4 acc[4][4];
#pragma unroll
    for (int i = 0; i < 4; ++i)
#pragma unroll
        for (int j = 0; j < 4; ++j) acc[i][j] = (f32x4){0.f, 0.f, 0.f, 0.f};

    const _Float16* pA = A + (size_t)p * KT * 4096;
    const _Float16* pB = Wt + (size_t)c * KT * 4096;
    const int cb0 = wid * 64;
    const int cb1 = 256 + wid * 64;
    const int kq  = (lane >> 4) * 128;
    const int l15 = lane & 15;
    const int l4  = (lane >> 4) << 2;

    for (int kt = 0; kt < KT; ++kt) {
        __syncthreads();
        gld_lds16(pA + (size_t)(cb0 + lane) * 8, As + cb0 * 8);
        gld_lds16(pA + (size_t)(cb1 + lane) * 8, As + cb1 * 8);
        gld_lds16(pB + (size_t)(cb0 + lane) * 8, Bs + cb0 * 8);
        gld_lds16(pB + (size_t)(cb1 + lane) * 8, Bs + cb1 * 8);
        pA += 4096; pB += 4096;
        __syncthreads();

        f16x8 af[4], bf[4];
#pragma unroll
        for (int i = 0; i < 4; ++i)
            af[i] = *(const f16x8*)(As + (size_t)((kq + wm + i * 16 + l15) << 3));
#pragma unroll
        for (int j = 0; j < 4; ++j)
            bf[j] = *(const f16x8*)(Bs + (size_t)((kq + wn + j * 16 + l15) << 3));
#pragma unroll
        for (int i = 0; i < 4; ++i)
#pragma unroll
            for (int j = 0; j < 4; ++j)
                acc[i][j] = __builtin_amdgcn_mfma_f32_16x16x32_f16(af[i], bf[j], acc[i][j], 0, 0, 0);
    }

    if (mode == 0) {
        // re-block C through LDS, two passes of 64 rows (tr = [64][132] f16)
        _Float16* tr = (_Float16*)smem;
#pragma unroll
        for (int pass = 0; pass < 2; ++pass) {
            __syncthreads();
            if (wm == pass * 64) {
#pragma unroll
                for (int i = 0; i < 4; ++i) {
#pragma unroll
                    for (int v = 0; v < 4; ++v) {
                        const int lr = i * 16 + l4 + v;
                        const float* brow = bias;
                        if (gbid) {
                            int m = p * 128 + pass * 64 + lr;
                            if (m >= M) m = M - 1;
                            brow = bias + (size_t)clampi(gbid[m], BB) * ldbias;
                        }
#pragma unroll
                        for (int j = 0; j < 4; ++j) {
                            const int cc = wn + j * 16 + l15;
                            float val = acc[i][j][v] + brow[c * 128 + cc];
                            if (relu) val = fmaxf(val, 0.f);
                            tr[lr * 132 + cc] = (_Float16)val;
                        }
                    }
                }
            }
            __syncthreads();
#pragma unroll
            for (int it = 0; it < 4; ++it) {
                const int id = it * 256 + tid;
                const int r  = id & 63;
                const int cg = id >> 6;
                f16x4 lo = *(const f16x4*)(tr + r * 132 + cg * 8);
                f16x4 hi = *(const f16x4*)(tr + r * 132 + cg * 8 + 4);
                f16x8 v8;
#pragma unroll
                for (int t = 0; t < 4; ++t) { v8[t] = lo[t]; v8[t + 4] = hi[t]; }
                const int kti = ktOff + (c << 2) + (cg >> 2);
                const int gr  = pass * 64 + r;
                size_t o = (((size_t)p * KTo + kti) * 4 + (cg & 3)) * 1024 + (size_t)gr * 8;
                *(f16x8*)((_Float16*)C + o) = v8;
            }
        }
    } else if (mode == 1) {
#pragma unroll
        for (int i = 0; i < 4; ++i) {
#pragma unroll
            for (int v = 0; v < 4; ++v) {
                const int m = p * 128 + wm + i * 16 + l4 + v;
                if (m >= M) continue;
                const float* brow = bias;
                if (gbid) brow = bias + (size_t)clampi(gbid[m], BB) * ldbias;
#pragma unroll
                for (int j = 0; j < 4; ++j) {
                    const int col = c * 128 + wn + j * 16 + l15;
                    float val = acc[i][j][v] + brow[col];
                    if (relu) val = fmaxf(val, 0.f);
                    ((float*)C)[(size_t)m * ldc + col] = val;
                }
            }
        }
    } else {
        // mode 2: fused coalesced scatter-add. 4 passes of 32 rows.
        float* trf = (float*)smem;   // [32][130] f32, 16640 B
#pragma unroll
        for (int pass = 0; pass < 4; ++pass) {
            __syncthreads();
            if (wm == ((pass >> 1) << 6)) {      // pass 0,1 -> wm 0; 2,3 -> wm 64
                const int i0 = (pass & 1) << 1;  // 0 or 2
#pragma unroll
                for (int ii = 0; ii < 2; ++ii) {
                    const int i = i0 + ii;
                    const int lr = ii * 16 + l4;   // row within 32 (plus v)
#pragma unroll
                    for (int v = 0; v < 4; ++v) {
#pragma unroll
                        for (int j = 0; j < 4; ++j) {
                            const int cc = wn + j * 16 + l15;
                            float val = acc[i][j][v] + bias[c * 128 + cc];
                            if (relu) val = fmaxf(val, 0.f);
                            trf[(lr + v) * 130 + cc] = val;
                        }
                    }
                }
            }
            __syncthreads();
            const int ebase = p * 128 + pass * 32;
#pragma unroll
            for (int it = 0; it < 16; ++it) {
                const int id = it * 256 + tid;   // 0..4095
                const int lr = id >> 7;          // 0..31
                const int colg = id & 127;
                const int el = ebase + lr;
                if (el < M) {
                    const int node = clampi(srow[el], NN);
                    atomicAdd(&agg[(size_t)node * 512 + c * 128 + colg],
                              trf[lr * 130 + colg]);
                }
            }
        }
    }
}

// ------------------------- helper kernels ----------------------------------

// fp32 w[N][Ksrc] -> blocked f16 [N/128][Kd/32] tiles.
// colmap mode: 0 plain (k<Ksrc), 1 e0 (k<19), 2 pack544 (k<9 | 32<=k<544 -> 9+(k-32))
__global__ void k_w2h_blk(const float* __restrict__ src, _Float16* __restrict__ dst,
                          int N, int Ksrc, int Kd, int mode)
{
    int t = blockIdx.x * blockDim.x + threadIdx.x;
    if (t >= N * Kd) return;
    int n = t / Kd, k = t - n * Kd;
    int sc = -1;
    if (mode == 0)      { if (k < Ksrc) sc = k; }
    else if (mode == 1) { if (k < 19) sc = k; }
    else                { if (k < 9) sc = k; else if (k >= 32 && k < 544) sc = 9 + (k - 32); }
    float v = (sc >= 0) ? src[(size_t)n * Ksrc + sc] : 0.f;
    int KT = Kd >> 5;
    int nt = n >> 7, r = n & 127, kt = k >> 5, kg = (k >> 3) & 3, ko = k & 7;
    dst[(((size_t)nt * KT + kt) * 4 + kg) * 1024 + (size_t)r * 8 + ko] = (_Float16)v;
}

// u_r[16,256] fp32
__global__ void k_u_r(const float* __restrict__ u, const float* __restrict__ w_sel,
                      const float* __restrict__ b_sel, float* __restrict__ u_r)
{
    int wave = (blockIdx.x * 256 + threadIdx.x) >> 6;
    int lane = threadIdx.x & 63;
    int b = wave >> 8, n = wave & 255;
    const float4* u4 = (const float4*)(u + (size_t)b * 4096);
    const float4* w4 = (const float4*)(w_sel + (size_t)n * 4096);
    float s = 0.f;
    for (int i = lane; i < 1024; i += 64) {
        float4 a = u4[i], c = w4[i];
        s += a.x * c.x + a.y * c.y + a.z * c.z + a.w * c.w;
    }
    for (int off = 32; off; off >>= 1) s += __shfl_down(s, off);
    if (lane == 0) u_r[b * 256 + n] = s + b_sel[n];
}

// ub[16][Nout] = u_r @ w[:, koff:koff+256]^T + b
__global__ void k_graph_bias(const float* __restrict__ u_r, const float* __restrict__ w,
                             const float* __restrict__ b, float* __restrict__ ub,
                             int Nout, int Ksrc, int koff)
{
    int wave = (blockIdx.x * 256 + threadIdx.x) >> 6;
    int lane = threadIdx.x & 63;
    if (wave >= 16 * Nout) return;
    int g = wave / Nout, n = wave - g * Nout;
    const float* ur = u_r + (size_t)g * 256;
    const float* wr = w + (size_t)n * Ksrc + koff;
    float s = 0.f;
#pragma unroll
    for (int i = 0; i < 4; ++i) s += ur[lane * 4 + i] * wr[lane * 4 + i];
    for (int off = 32; off; off >>= 1) s += __shfl_down(s, off);
    if (lane == 0) ub[(size_t)g * Nout + n] = s + b[n];
}

__global__ void k_gbe(const int* __restrict__ row, const int* __restrict__ batch,
                      int* __restrict__ gbe)
{
    int e = blockIdx.x * blockDim.x + threadIdx.x;
    if (e < EE) gbe[e] = clampi(batch[clampi(row[e], NN)], BB);
}

// e_in blocked [MT][1]: cols = [x[row](9) | x[col](9) | ea | 0..]
__global__ void k_gather_edge_blk(const float* __restrict__ x, const float* __restrict__ ea,
                                  const int* __restrict__ row, const int* __restrict__ col,
                                  _Float16* __restrict__ dst, int e0, int ec, int MTR)
{
    int t = blockIdx.x * blockDim.x + threadIdx.x;
    if (t >= MTR * 4) return;
    int r = t >> 2, kg = t & 3;
    int e = e0 + r; int emax = e0 + ec - 1;
    if (e > emax) e = emax;
    int ri = clampi(row[e], NN), ci = clampi(col[e], NN);
    f16x8 v;
#pragma unroll
    for (int j = 0; j < 8; ++j) {
        int cc = kg * 8 + j;
        float fv = 0.f;
        if (cc < 9)       fv = x[(size_t)ri * 9 + cc];
        else if (cc < 18) fv = x[(size_t)ci * 9 + (cc - 9)];
        else if (cc == 18) fv = ea[e];
        v[j] = (_Float16)fv;
    }
    *(f16x8*)(dst + (size_t)(r >> 7) * 4096 + (size_t)kg * 1024 + (size_t)(r & 127) * 8) = v;
}

// ninb kt0 (x[col] | pad) blocked; kt1..16 written by ew4's epilogue
__global__ void k_gather_nin0(const float* __restrict__ x, const int* __restrict__ col,
                              _Float16* __restrict__ dst, int e0, int ec, int MTR)
{
    int t = blockIdx.x * blockDim.x + threadIdx.x;
    if (t >= MTR * 4) return;
    int r = t >> 2, kg = t & 3;
    int e = e0 + r; int emax = e0 + ec - 1;
    if (e > emax) e = emax;
    int ci = clampi(col[e], NN);
    f16x8 v = (f16x8)(_Float16)0.f;
#pragma unroll
    for (int j = 0; j < 8; ++j) {
        int cc = kg * 8 + j;
        if (cc < 9) v[j] = (_Float16)x[(size_t)ci * 9 + cc];
    }
    *(f16x8*)(dst + ((size_t)(r >> 7) * 17) * 4096 + (size_t)kg * 1024 + (size_t)(r & 127) * 8) = v;
}

// m_in blocked [MTm][17]: cols = [x(9)|pad23 | agg/cnt(512)]
__global__ void k_gather_min(const float* __restrict__ x, const float* __restrict__ agg,
                             const float* __restrict__ cnt, _Float16* __restrict__ dst, int MTR)
{
    int t = blockIdx.x * blockDim.x + threadIdx.x;
    if (t >= MTR * 68) return;
    int r = t / 68, q = t - r * 68;
    int kt = q >> 2, kg = q & 3;
    int n = r < NN ? r : NN - 1;
    f16x8 v = (f16x8)(_Float16)0.f;
    if (kt == 0) {
#pragma unroll
        for (int j = 0; j < 8; ++j) {
            int cc = kg * 8 + j;
            if (cc < 9) v[j] = (_Float16)x[(size_t)n * 9 + cc];
        }
    } else {
        float inv = 1.f / fmaxf(cnt[n], 1.f);
        int cbase = (kt - 1) * 32 + kg * 8;
        const float4* ap = (const float4*)(agg + (size_t)n * 512 + cbase);
        float4 a0 = ap[0], a1 = ap[1];
        v[0] = (_Float16)(a0.x * inv); v[1] = (_Float16)(a0.y * inv);
        v[2] = (_Float16)(a0.z * inv); v[3] = (_Float16)(a0.w * inv);
        v[4] = (_Float16)(a1.x * inv); v[5] = (_Float16)(a1.y * inv);
        v[6] = (_Float16)(a1.z * inv); v[7] = (_Float16)(a1.w * inv);
    }
    *(f16x8*)(dst + ((size_t)(r >> 7) * 17 + kt) * 4096 + (size_t)kg * 1024 + (size_t)(r & 127) * 8) = v;
}

__global__ void k_count(const int* __restrict__ row, float* __restrict__ cnt)
{
    int e = blockIdx.x * blockDim.x + threadIdx.x;
    if (e < EE) atomicAdd(&cnt[clampi(row[e], NN)], 1.f);
}

// out[n] = h2[n,:] . mw1 + mb1
__global__ void k_final(const float* __restrict__ h2, const float* __restrict__ mw1,
                        const float* __restrict__ mb1, float* __restrict__ out)
{
    int wave = (blockIdx.x * 256 + threadIdx.x) >> 6;
    int lane = threadIdx.x & 63;
    if (wave >= NN) return;
    const float4* h4 = (const float4*)(h2 + (size_t)wave * 512);
    const float4* w4 = (const float4*)mw1;
    float s = 0.f;
#pragma unroll
    for (int i = 0; i < 2; ++i) {
        int f = lane * 2 + i;
        float4 a = h4[f], b = w4[f];
        s += a.x * b.x + a.y * b.y + a.z * b.z + a.w * b.w;
    }
    for (int off = 32; off; off >>= 1) s += __shfl_down(s, off);
    if (lane == 0) out[wave] = s + mb1[0];
}

// ------------------------------- host --------------------------------------

#define GRID1(n) dim3(((n) + 255) / 256)

static inline void gemmB(hipStream_t s, const _Float16* A, const _Float16* Wt, int KT,
                         const float* bias, int ldbias, const int* gbid,
                         void* C, int KTo, int ktOff, int ldc,
                         const int* srow, float* agg,
                         int M, int MT, int NT, int relu, int mode)
{
    hipLaunchKernelGGL(gemm_blk, dim3(NT, MT), dim3(256), 0, s,
                       A, Wt, KT, bias, ldbias, gbid, C, KTo, ktOff, ldc,
                       srow, agg, M, relu, mode);
}

extern "C" void kernel_launch(void* const* d_in, const int* in_sizes, int n_in,
                              void* d_out, int out_size, void* d_ws, size_t ws_size,
                              hipStream_t stream)
{
    const float* x     = (const float*)d_in[0];
    const int*   ei    = (const int*)d_in[1];
    const float* ea    = (const float*)d_in[2];
    const float* u     = (const float*)d_in[3];
    const int*   batch = (const int*)d_in[4];
    const float* w_sel = (const float*)d_in[5];
    const float* b_sel = (const float*)d_in[6];
    const float* ew0 = (const float*)d_in[7];   const float* eb0 = (const float*)d_in[8];
    const float* ew1 = (const float*)d_in[9];   const float* eb1 = (const float*)d_in[10];
    const float* ew2 = (const float*)d_in[11];  const float* eb2 = (const float*)d_in[12];
    const float* ew3 = (const float*)d_in[13];  const float* eb3 = (const float*)d_in[14];
    const float* ew4 = (const float*)d_in[15];  const float* eb4 = (const float*)d_in[16];
    const float* nw0 = (const float*)d_in[17];  const float* nb0 = (const float*)d_in[18];
    const float* nw1 = (const float*)d_in[19];  const float* nb1 = (const float*)d_in[20];
    const float* mw0 = (const float*)d_in[21];  const float* mb0 = (const float*)d_in[22];
    const float* mw1 = (const float*)d_in[23];  const float* mb1 = (const float*)d_in[24];

    const int* row = ei;
    const int* col = ei + EE;

    char* W = (char*)d_ws;
    size_t off = 0;
    auto alloc = [&](size_t bytes) -> char* {
        char* p = W + off;
        off = (off + bytes + 255) & ~(size_t)255;
        return p;
    };
    float*    cnt  = (float*)alloc(20000 * 4);
    float*    agg  = (float*)alloc((size_t)NN * 512 * 4);
    const size_t zeroBytes = off;
    float*    u_r  = (float*)alloc(16 * 256 * 4);
    float*    ub0  = (float*)alloc(16 * 1024 * 4);
    float*    ubm  = (float*)alloc(16 * 512 * 4);
    int*      gbe  = (int*)alloc((size_t)EE * 4);
    _Float16* wh0  = (_Float16*)alloc((size_t)8 * 1 * 4096 * 2);
    _Float16* wh1  = (_Float16*)alloc((size_t)8 * 32 * 4096 * 2);
    _Float16* wh2  = (_Float16*)alloc((size_t)8 * 32 * 4096 * 2);
    _Float16* wh3  = (_Float16*)alloc((size_t)8 * 32 * 4096 * 2);
    _Float16* wh4  = (_Float16*)alloc((size_t)4 * 32 * 4096 * 2);
    _Float16* whn0 = (_Float16*)alloc((size_t)4 * 17 * 4096 * 2);
    _Float16* whn1 = (_Float16*)alloc((size_t)4 * 16 * 4096 * 2);
    _Float16* whm0 = (_Float16*)alloc((size_t)4 * 17 * 4096 * 2);
    const int MTm = (NN + 127) / 128;           // 157
    float*    h2   = (float*)alloc((size_t)NN * 512 * 4);
    _Float16* m_in = (_Float16*)alloc((size_t)MTm * 17 * 4096 * 2);
    const size_t fixedBytes = off;

    // choose edge chunk (depends only on ws_size -> capture-safe).
    // EC=25000: chunk buffers ~132MB; total ~245MB (fits; verified R6).
    static const int ecOpts[] = {25000, 12500, 10000, 5000};
    int EC = 5000;
    for (int i = 0; i < 4; ++i) {
        int ec = ecOpts[i];
        size_t MTRc = (size_t)((ec + 127) / 128) * 128;
        size_t need = fixedBytes + MTRc * 32 * 2 + 2 * (MTRc * 1024 * 2)
                    + MTRc * 544 * 2 + 4096;
        if (need <= ws_size) { EC = ec; break; }
    }
    const int MT  = (EC + 127) / 128;
    const size_t MTR = (size_t)MT * 128;
    _Float16* e_in = (_Float16*)alloc(MTR * 32 * 2);    // [MT][1]
    _Float16* ping = (_Float16*)alloc(MTR * 1024 * 2);  // [MT][32]
    _Float16* pong = (_Float16*)alloc(MTR * 1024 * 2);  // [MT][32]
    _Float16* ninb = (_Float16*)alloc(MTR * 544 * 2);   // [MT][17]
    const int NCH = (EE + EC - 1) / EC;

    (void)hipMemsetAsync(W, 0, zeroBytes, stream);

    hipLaunchKernelGGL(k_u_r, dim3(1024), dim3(256), 0, stream, u, w_sel, b_sel, u_r);
    hipLaunchKernelGGL(k_graph_bias, GRID1(16 * 1024 * 64), dim3(256), 0, stream,
                       u_r, ew0, eb0, ub0, 1024, 275, 19);
    hipLaunchKernelGGL(k_graph_bias, GRID1(16 * 512 * 64), dim3(256), 0, stream,
                       u_r, mw0, mb0, ubm, 512, 777, 521);
    hipLaunchKernelGGL(k_gbe, GRID1(EE), dim3(256), 0, stream, row, batch, gbe);

    auto pack = [&](const float* w, _Float16* wh, int N, int Ksrc, int Kd, int mode) {
        hipLaunchKernelGGL(k_w2h_blk, GRID1(N * Kd), dim3(256), 0, stream, w, wh, N, Ksrc, Kd, mode);
    };
    pack(ew0, wh0, 1024, 275, 32, 1);
    pack(ew1, wh1, 1024, 1024, 1024, 0);
    pack(ew2, wh2, 1024, 1024, 1024, 0);
    pack(ew3, wh3, 1024, 1024, 1024, 0);
    pack(ew4, wh4, 512, 1024, 1024, 0);
    pack(nw0, whn0, 512, 521, 544, 2);
    pack(nw1, whn1, 512, 512, 512, 0);
    pack(mw0, whm0, 512, 777, 544, 2);

    hipLaunchKernelGGL(k_count, GRID1(EE), dim3(256), 0, stream, row, cnt);

    for (int ch = 0; ch < NCH; ++ch) {
        int e0 = ch * EC;
        int ec = EC; if (e0 + ec > EE) ec = EE - e0;
        hipLaunchKernelGGL(k_gather_edge_blk, GRID1((int)MTR * 4), dim3(256), 0, stream,
                           x, ea, row, col, e_in, e0, ec, (int)MTR);
        // l0: K=32, per-graph bias ub0
        gemmB(stream, e_in, wh0, 1, ub0, 1024, gbe + e0, ping, 32, 0, 0, nullptr, nullptr,
              ec, MT, 8, 1, 0);
        gemmB(stream, ping, wh1, 32, eb1, 0, nullptr, pong, 32, 0, 0, nullptr, nullptr,
              ec, MT, 8, 1, 0);
        gemmB(stream, pong, wh2, 32, eb2, 0, nullptr, ping, 32, 0, 0, nullptr, nullptr,
              ec, MT, 8, 1, 0);
        gemmB(stream, ping, wh3, 32, eb3, 0, nullptr, pong, 32, 0, 0, nullptr, nullptr,
              ec, MT, 8, 1, 0);
        // ew4 -> ninb (blocked, kt offset 1), no relu on edge_out
        gemmB(stream, pong, wh4, 32, eb4, 0, nullptr, ninb, 17, 1, 0, nullptr, nullptr,
              ec, MT, 4, 0, 0);
        hipLaunchKernelGGL(k_gather_nin0, GRID1((int)MTR * 4), dim3(256), 0, stream,
                           x, col, ninb, e0, ec, (int)MTR);
        gemmB(stream, ninb, whn0, 17, nb0, 0, nullptr, ping, 16, 0, 0, nullptr, nullptr,
              ec, MT, 4, 1, 0);
        // n1: fused COALESCED scatter-add into agg (mode 2)
        gemmB(stream, ping, whn1, 16, nb1, 0, nullptr, nullptr, 0, 0, 0, row + e0, agg,
              ec, MT, 4, 1, 2);
    }

    hipLaunchKernelGGL(k_gather_min, GRID1((int)(MTm * 128) * 68), dim3(256), 0, stream,
                       x, agg, cnt, m_in, MTm * 128);
    // m0: f32 row-major out, per-graph bias ubm (gbid = batch)
    gemmB(stream, m_in, whm0, 17, ubm, 512, batch, h2, 0, 0, 512, nullptr, nullptr,
          NN, MTm, 4, 1, 1);
    hipLaunchKernelGGL(k_final, dim3((NN + 3) / 4), dim3(256), 0, stream,
                       h2, mw1, mb1, (float*)d_out);
}

// Round 9
// 2175.174 us; speedup vs baseline: 1.2050x; 1.1707x over previous
//
#include <hip/hip_runtime.h>

// ---------------------------------------------------------------------------
// OGRENet GraphNet block — f16 MFMA with BLOCKED operand layout.
// Blocked layout (f16): offset(m,k) = ((mt*KT + kt)*4 + kg)*1024 + r*8 + ko
//   mt=m>>7, r=m&127, kt=k>>5, kg=(k>>3)&3, ko=k&7.   (tile = 128x32 = 8KB)
// Staging reads are 1KB-contiguous per global_load_lds; frag reads conflict-free.
// MODE is a TEMPLATE param: each epilogue gets its own register allocation
// (R8 lesson: one kernel w/ runtime mode -> worst-case VGPR taxes all GEMMs).
//  mode 0: re-block C via 2-pass LDS transpose (f16, conflict-free)
//  mode 1: f32 row-major
//  mode 2: fused scatter-add, 4-pass f32 LDS transpose -> COALESCED atomics
// XCD swizzle: 8 column-blocks of one M-panel land on the same XCD.
// [R7 lesson: rocprof serialized replay overstates atomic kernels ~20x.]
// ---------------------------------------------------------------------------

#define NN 20000
#define EE 100000
#define BB 16

typedef _Float16 f16x8 __attribute__((ext_vector_type(8)));
typedef _Float16 f16x4 __attribute__((ext_vector_type(4)));
typedef float f32x4 __attribute__((ext_vector_type(4)));

__device__ __forceinline__ int clampi(int v, int hi) {
    return v < 0 ? 0 : (v >= hi ? hi - 1 : v);
}

__device__ __forceinline__ void gld_lds16(const void* g, void* l) {
    __builtin_amdgcn_global_load_lds(
        (const __attribute__((address_space(1))) unsigned int*)g,
        (__attribute__((address_space(3))) unsigned int*)l, 16, 0, 0);
}

// ------------------------- blocked f16 MFMA GEMM ---------------------------
template <int MODE>
__global__ __launch_bounds__(256) void gemm_blk(
    const _Float16* __restrict__ A,      // blocked [MT][KT]
    const _Float16* __restrict__ Wt,     // blocked [NT][KT]
    int KT,
    const float* __restrict__ bias, int ldbias, const int* __restrict__ gbid,
    void* __restrict__ C, int KTo, int ktOff,   // mode 0: blocked f16 out
    int ldc,                                    // mode 1: f32 row-major out
    const int* __restrict__ srow, float* __restrict__ agg,  // mode 2
    int M, int relu)
{
    __shared__ char smem[16896];   // staging 16384 | m0 tr 64*132*2 | m2 trf 32*130*4
    _Float16* As = (_Float16*)smem;
    _Float16* Bs = As + 4096;

    const int tid  = threadIdx.x;
    const int lane = tid & 63;
    const int wid  = tid >> 6;
    const int wm = (wid & 1) << 6;
    const int wn = (wid >> 1) << 6;

    // XCD swizzle: panel p's column-blocks share f%8 (same XCD)
    const int nb = gridDim.x;
    const int MT = gridDim.y;
    int f = blockIdx.y * nb + blockIdx.x;
    const int MT8 = MT & ~7;
    int p, c;
    if (f < MT8 * nb) {
        c = (f >> 3) % nb;
        p = (f & 7) + 8 * ((f >> 3) / nb);
    } else {
        int g = f - MT8 * nb;
        p = MT8 + g / nb;
        c = g % nb;
    }

    f32x4 acc[4][4];
#pragma unroll
    for (int i = 0; i < 4; ++i)
#pragma unroll
        for (int j = 0; j < 4; ++j) acc[i][j] = (f32x4){0.f, 0.f, 0.f, 0.f};

    const _Float16* pA = A + (size_t)p * KT * 4096;
    const _Float16* pB = Wt + (size_t)c * KT * 4096;
    const int cb0 = wid * 64;
    const int cb1 = 256 + wid * 64;
    const int kq  = (lane >> 4) * 128;
    const int l15 = lane & 15;
    const int l4  = (lane >> 4) << 2;

    for (int kt = 0; kt < KT; ++kt) {
        __syncthreads();
        gld_lds16(pA + (size_t)(cb0 + lane) * 8, As + cb0 * 8);
        gld_lds16(pA + (size_t)(cb1 + lane) * 8, As + cb1 * 8);
        gld_lds16(pB + (size_t)(cb0 + lane) * 8, Bs + cb0 * 8);
        gld_lds16(pB + (size_t)(cb1 + lane) * 8, Bs + cb1 * 8);
        pA += 4096; pB += 4096;
        __syncthreads();

        f16x8 af[4], bf[4];
#pragma unroll
        for (int i = 0; i < 4; ++i)
            af[i] = *(const f16x8*)(As + (size_t)((kq + wm + i * 16 + l15) << 3));
#pragma unroll
        for (int j = 0; j < 4; ++j)
            bf[j] = *(const f16x8*)(Bs + (size_t)((kq + wn + j * 16 + l15) << 3));
#pragma unroll
        for (int i = 0; i < 4; ++i)
#pragma unroll
            for (int j = 0; j < 4; ++j)
                acc[i][j] = __builtin_amdgcn_mfma_f32_16x16x32_f16(af[i], bf[j], acc[i][j], 0, 0, 0);
    }

    if (MODE == 0) {
        // re-block C through LDS, two passes of 64 rows (tr = [64][132] f16)
        _Float16* tr = (_Float16*)smem;
#pragma unroll
        for (int pass = 0; pass < 2; ++pass) {
            __syncthreads();
            if (wm == pass * 64) {
#pragma unroll
                for (int i = 0; i < 4; ++i) {
#pragma unroll
                    for (int v = 0; v < 4; ++v) {
                        const int lr = i * 16 + l4 + v;
                        const float* brow = bias;
                        if (gbid) {
                            int m = p * 128 + pass * 64 + lr;
                            if (m >= M) m = M - 1;
                            brow = bias + (size_t)clampi(gbid[m], BB) * ldbias;
                        }
#pragma unroll
                        for (int j = 0; j < 4; ++j) {
                            const int cc = wn + j * 16 + l15;
                            float val = acc[i][j][v] + brow[c * 128 + cc];
                            if (relu) val = fmaxf(val, 0.f);
                            tr[lr * 132 + cc] = (_Float16)val;
                        }
                    }
                }
            }
            __syncthreads();
#pragma unroll
            for (int it = 0; it < 4; ++it) {
                const int id = it * 256 + tid;
                const int r  = id & 63;
                const int cg = id >> 6;
                f16x4 lo = *(const f16x4*)(tr + r * 132 + cg * 8);
                f16x4 hi = *(const f16x4*)(tr + r * 132 + cg * 8 + 4);
                f16x8 v8;
#pragma unroll
                for (int t = 0; t < 4; ++t) { v8[t] = lo[t]; v8[t + 4] = hi[t]; }
                const int kti = ktOff + (c << 2) + (cg >> 2);
                const int gr  = pass * 64 + r;
                size_t o = (((size_t)p * KTo + kti) * 4 + (cg & 3)) * 1024 + (size_t)gr * 8;
                *(f16x8*)((_Float16*)C + o) = v8;
            }
        }
    } else if (MODE == 1) {
#pragma unroll
        for (int i = 0; i < 4; ++i) {
#pragma unroll
            for (int v = 0; v < 4; ++v) {
                const int m = p * 128 + wm + i * 16 + l4 + v;
                if (m >= M) continue;
                const float* brow = bias;
                if (gbid) brow = bias + (size_t)clampi(gbid[m], BB) * ldbias;
#pragma unroll
                for (int j = 0; j < 4; ++j) {
                    const int col = c * 128 + wn + j * 16 + l15;
                    float val = acc[i][j][v] + brow[col];
                    if (relu) val = fmaxf(val, 0.f);
                    ((float*)C)[(size_t)m * ldc + col] = val;
                }
            }
        }
    } else {
        // mode 2: fused coalesced scatter-add. 4 passes of 32 rows.
        float* trf = (float*)smem;   // [32][130] f32, 16640 B
#pragma unroll
        for (int pass = 0; pass < 4; ++pass) {
            __syncthreads();
            if (wm == ((pass >> 1) << 6)) {      // pass 0,1 -> wm 0; 2,3 -> wm 64
                const int i0 = (pass & 1) << 1;  // 0 or 2
#pragma unroll
                for (int ii = 0; ii < 2; ++ii) {
                    const int i = i0 + ii;
                    const int lr = ii * 16 + l4;
#pragma unroll
                    for (int v = 0; v < 4; ++v) {
#pragma unroll
                        for (int j = 0; j < 4; ++j) {
                            const int cc = wn + j * 16 + l15;
                            float val = acc[i][j][v] + bias[c * 128 + cc];
                            if (relu) val = fmaxf(val, 0.f);
                            trf[(lr + v) * 130 + cc] = val;
                        }
                    }
                }
            }
            __syncthreads();
            const int ebase = p * 128 + pass * 32;
#pragma unroll
            for (int it = 0; it < 16; ++it) {
                const int id = it * 256 + tid;   // 0..4095
                const int lr = id >> 7;          // 0..31
                const int colg = id & 127;
                const int el = ebase + lr;
                if (el < M) {
                    const int node = clampi(srow[el], NN);
                    atomicAdd(&agg[(size_t)node * 512 + c * 128 + colg],
                              trf[lr * 130 + colg]);
                }
            }
        }
    }
}

// ------------------------- helper kernels ----------------------------------

// fp32 w[N][Ksrc] -> blocked f16 [N/128][Kd/32] tiles.
// colmap mode: 0 plain (k<Ksrc), 1 e0 (k<19), 2 pack544 (k<9 | 32<=k<544 -> 9+(k-32))
__global__ void k_w2h_blk(const float* __restrict__ src, _Float16* __restrict__ dst,
                          int N, int Ksrc, int Kd, int mode)
{
    int t = blockIdx.x * blockDim.x + threadIdx.x;
    if (t >= N * Kd) return;
    int n = t / Kd, k = t - n * Kd;
    int sc = -1;
    if (mode == 0)      { if (k < Ksrc) sc = k; }
    else if (mode == 1) { if (k < 19) sc = k; }
    else                { if (k < 9) sc = k; else if (k >= 32 && k < 544) sc = 9 + (k - 32); }
    float v = (sc >= 0) ? src[(size_t)n * Ksrc + sc] : 0.f;
    int KT = Kd >> 5;
    int nt = n >> 7, r = n & 127, kt = k >> 5, kg = (k >> 3) & 3, ko = k & 7;
    dst[(((size_t)nt * KT + kt) * 4 + kg) * 1024 + (size_t)r * 8 + ko] = (_Float16)v;
}

// u_r[16,256] fp32
__global__ void k_u_r(const float* __restrict__ u, const float* __restrict__ w_sel,
                      const float* __restrict__ b_sel, float* __restrict__ u_r)
{
    int wave = (blockIdx.x * 256 + threadIdx.x) >> 6;
    int lane = threadIdx.x & 63;
    int b = wave >> 8, n = wave & 255;
    const float4* u4 = (const float4*)(u + (size_t)b * 4096);
    const float4* w4 = (const float4*)(w_sel + (size_t)n * 4096);
    float s = 0.f;
    for (int i = lane; i < 1024; i += 64) {
        float4 a = u4[i], c = w4[i];
        s += a.x * c.x + a.y * c.y + a.z * c.z + a.w * c.w;
    }
    for (int off = 32; off; off >>= 1) s += __shfl_down(s, off);
    if (lane == 0) u_r[b * 256 + n] = s + b_sel[n];
}

// ub[16][Nout] = u_r @ w[:, koff:koff+256]^T + b
__global__ void k_graph_bias(const float* __restrict__ u_r, const float* __restrict__ w,
                             const float* __restrict__ b, float* __restrict__ ub,
                             int Nout, int Ksrc, int koff)
{
    int wave = (blockIdx.x * 256 + threadIdx.x) >> 6;
    int lane = threadIdx.x & 63;
    if (wave >= 16 * Nout) return;
    int g = wave / Nout, n = wave - g * Nout;
    const float* ur = u_r + (size_t)g * 256;
    const float* wr = w + (size_t)n * Ksrc + koff;
    float s = 0.f;
#pragma unroll
    for (int i = 0; i < 4; ++i) s += ur[lane * 4 + i] * wr[lane * 4 + i];
    for (int off = 32; off; off >>= 1) s += __shfl_down(s, off);
    if (lane == 0) ub[(size_t)g * Nout + n] = s + b[n];
}

__global__ void k_gbe(const int* __restrict__ row, const int* __restrict__ batch,
                      int* __restrict__ gbe)
{
    int e = blockIdx.x * blockDim.x + threadIdx.x;
    if (e < EE) gbe[e] = clampi(batch[clampi(row[e], NN)], BB);
}

// e_in blocked [MT][1]: cols = [x[row](9) | x[col](9) | ea | 0..]
__global__ void k_gather_edge_blk(const float* __restrict__ x, const float* __restrict__ ea,
                                  const int* __restrict__ row, const int* __restrict__ col,
                                  _Float16* __restrict__ dst, int e0, int ec, int MTR)
{
    int t = blockIdx.x * blockDim.x + threadIdx.x;
    if (t >= MTR * 4) return;
    int r = t >> 2, kg = t & 3;
    int e = e0 + r; int emax = e0 + ec - 1;
    if (e > emax) e = emax;
    int ri = clampi(row[e], NN), ci = clampi(col[e], NN);
    f16x8 v;
#pragma unroll
    for (int j = 0; j < 8; ++j) {
        int cc = kg * 8 + j;
        float fv = 0.f;
        if (cc < 9)       fv = x[(size_t)ri * 9 + cc];
        else if (cc < 18) fv = x[(size_t)ci * 9 + (cc - 9)];
        else if (cc == 18) fv = ea[e];
        v[j] = (_Float16)fv;
    }
    *(f16x8*)(dst + (size_t)(r >> 7) * 4096 + (size_t)kg * 1024 + (size_t)(r & 127) * 8) = v;
}

// ninb kt0 (x[col] | pad) blocked; kt1..16 written by ew4's epilogue
__global__ void k_gather_nin0(const float* __restrict__ x, const int* __restrict__ col,
                              _Float16* __restrict__ dst, int e0, int ec, int MTR)
{
    int t = blockIdx.x * blockDim.x + threadIdx.x;
    if (t >= MTR * 4) return;
    int r = t >> 2, kg = t & 3;
    int e = e0 + r; int emax = e0 + ec - 1;
    if (e > emax) e = emax;
    int ci = clampi(col[e], NN);
    f16x8 v = (f16x8)(_Float16)0.f;
#pragma unroll
    for (int j = 0; j < 8; ++j) {
        int cc = kg * 8 + j;
        if (cc < 9) v[j] = (_Float16)x[(size_t)ci * 9 + cc];
    }
    *(f16x8*)(dst + ((size_t)(r >> 7) * 17) * 4096 + (size_t)kg * 1024 + (size_t)(r & 127) * 8) = v;
}

// m_in blocked [MTm][17]: cols = [x(9)|pad23 | agg/cnt(512)]
__global__ void k_gather_min(const float* __restrict__ x, const float* __restrict__ agg,
                             const float* __restrict__ cnt, _Float16* __restrict__ dst, int MTR)
{
    int t = blockIdx.x * blockDim.x + threadIdx.x;
    if (t >= MTR * 68) return;
    int r = t / 68, q = t - r * 68;
    int kt = q >> 2, kg = q & 3;
    int n = r < NN ? r : NN - 1;
    f16x8 v = (f16x8)(_Float16)0.f;
    if (kt == 0) {
#pragma unroll
        for (int j = 0; j < 8; ++j) {
            int cc = kg * 8 + j;
            if (cc < 9) v[j] = (_Float16)x[(size_t)n * 9 + cc];
        }
    } else {
        float inv = 1.f / fmaxf(cnt[n], 1.f);
        int cbase = (kt - 1) * 32 + kg * 8;
        const float4* ap = (const float4*)(agg + (size_t)n * 512 + cbase);
        float4 a0 = ap[0], a1 = ap[1];
        v[0] = (_Float16)(a0.x * inv); v[1] = (_Float16)(a0.y * inv);
        v[2] = (_Float16)(a0.z * inv); v[3] = (_Float16)(a0.w * inv);
        v[4] = (_Float16)(a1.x * inv); v[5] = (_Float16)(a1.y * inv);
        v[6] = (_Float16)(a1.z * inv); v[7] = (_Float16)(a1.w * inv);
    }
    *(f16x8*)(dst + ((size_t)(r >> 7) * 17 + kt) * 4096 + (size_t)kg * 1024 + (size_t)(r & 127) * 8) = v;
}

__global__ void k_count(const int* __restrict__ row, float* __restrict__ cnt)
{
    int e = blockIdx.x * blockDim.x + threadIdx.x;
    if (e < EE) atomicAdd(&cnt[clampi(row[e], NN)], 1.f);
}

// out[n] = h2[n,:] . mw1 + mb1
__global__ void k_final(const float* __restrict__ h2, const float* __restrict__ mw1,
                        const float* __restrict__ mb1, float* __restrict__ out)
{
    int wave = (blockIdx.x * 256 + threadIdx.x) >> 6;
    int lane = threadIdx.x & 63;
    if (wave >= NN) return;
    const float4* h4 = (const float4*)(h2 + (size_t)wave * 512);
    const float4* w4 = (const float4*)mw1;
    float s = 0.f;
#pragma unroll
    for (int i = 0; i < 2; ++i) {
        int f = lane * 2 + i;
        float4 a = h4[f], b = w4[f];
        s += a.x * b.x + a.y * b.y + a.z * b.z + a.w * b.w;
    }
    for (int off = 32; off; off >>= 1) s += __shfl_down(s, off);
    if (lane == 0) out[wave] = s + mb1[0];
}

// ------------------------------- host --------------------------------------

#define GRID1(n) dim3(((n) + 255) / 256)

static inline void gemmB0(hipStream_t s, const _Float16* A, const _Float16* Wt, int KT,
                          const float* bias, int ldbias, const int* gbid,
                          void* C, int KTo, int ktOff,
                          int M, int MT, int NT, int relu)
{
    hipLaunchKernelGGL(gemm_blk<0>, dim3(NT, MT), dim3(256), 0, s,
                       A, Wt, KT, bias, ldbias, gbid, C, KTo, ktOff, 0,
                       nullptr, nullptr, M, relu);
}
static inline void gemmB1(hipStream_t s, const _Float16* A, const _Float16* Wt, int KT,
                          const float* bias, int ldbias, const int* gbid,
                          void* C, int ldc, int M, int MT, int NT, int relu)
{
    hipLaunchKernelGGL(gemm_blk<1>, dim3(NT, MT), dim3(256), 0, s,
                       A, Wt, KT, bias, ldbias, gbid, C, 0, 0, ldc,
                       nullptr, nullptr, M, relu);
}
static inline void gemmB2(hipStream_t s, const _Float16* A, const _Float16* Wt, int KT,
                          const float* bias, const int* srow, float* agg,
                          int M, int MT, int NT, int relu)
{
    hipLaunchKernelGGL(gemm_blk<2>, dim3(NT, MT), dim3(256), 0, s,
                       A, Wt, KT, bias, 0, nullptr, nullptr, 0, 0, 0,
                       srow, agg, M, relu);
}

extern "C" void kernel_launch(void* const* d_in, const int* in_sizes, int n_in,
                              void* d_out, int out_size, void* d_ws, size_t ws_size,
                              hipStream_t stream)
{
    const float* x     = (const float*)d_in[0];
    const int*   ei    = (const int*)d_in[1];
    const float* ea    = (const float*)d_in[2];
    const float* u     = (const float*)d_in[3];
    const int*   batch = (const int*)d_in[4];
    const float* w_sel = (const float*)d_in[5];
    const float* b_sel = (const float*)d_in[6];
    const float* ew0 = (const float*)d_in[7];   const float* eb0 = (const float*)d_in[8];
    const float* ew1 = (const float*)d_in[9];   const float* eb1 = (const float*)d_in[10];
    const float* ew2 = (const float*)d_in[11];  const float* eb2 = (const float*)d_in[12];
    const float* ew3 = (const float*)d_in[13];  const float* eb3 = (const float*)d_in[14];
    const float* ew4 = (const float*)d_in[15];  const float* eb4 = (const float*)d_in[16];
    const float* nw0 = (const float*)d_in[17];  const float* nb0 = (const float*)d_in[18];
    const float* nw1 = (const float*)d_in[19];  const float* nb1 = (const float*)d_in[20];
    const float* mw0 = (const float*)d_in[21];  const float* mb0 = (const float*)d_in[22];
    const float* mw1 = (const float*)d_in[23];  const float* mb1 = (const float*)d_in[24];

    const int* row = ei;
    const int* col = ei + EE;

    char* W = (char*)d_ws;
    size_t off = 0;
    auto alloc = [&](size_t bytes) -> char* {
        char* p = W + off;
        off = (off + bytes + 255) & ~(size_t)255;
        return p;
    };
    float*    cnt  = (float*)alloc(20000 * 4);
    float*    agg  = (float*)alloc((size_t)NN * 512 * 4);
    const size_t zeroBytes = off;
    float*    u_r  = (float*)alloc(16 * 256 * 4);
    float*    ub0  = (float*)alloc(16 * 1024 * 4);
    float*    ubm  = (float*)alloc(16 * 512 * 4);
    int*      gbe  = (int*)alloc((size_t)EE * 4);
    _Float16* wh0  = (_Float16*)alloc((size_t)8 * 1 * 4096 * 2);
    _Float16* wh1  = (_Float16*)alloc((size_t)8 * 32 * 4096 * 2);
    _Float16* wh2  = (_Float16*)alloc((size_t)8 * 32 * 4096 * 2);
    _Float16* wh3  = (_Float16*)alloc((size_t)8 * 32 * 4096 * 2);
    _Float16* wh4  = (_Float16*)alloc((size_t)4 * 32 * 4096 * 2);
    _Float16* whn0 = (_Float16*)alloc((size_t)4 * 17 * 4096 * 2);
    _Float16* whn1 = (_Float16*)alloc((size_t)4 * 16 * 4096 * 2);
    _Float16* whm0 = (_Float16*)alloc((size_t)4 * 17 * 4096 * 2);
    const int MTm = (NN + 127) / 128;           // 157
    float*    h2   = (float*)alloc((size_t)NN * 512 * 4);
    _Float16* m_in = (_Float16*)alloc((size_t)MTm * 17 * 4096 * 2);
    const size_t fixedBytes = off;

    // choose edge chunk (depends only on ws_size -> capture-safe).
    static const int ecOpts[] = {25000, 12500, 10000, 5000};
    int EC = 5000;
    for (int i = 0; i < 4; ++i) {
        int ec = ecOpts[i];
        size_t MTRc = (size_t)((ec + 127) / 128) * 128;
        size_t need = fixedBytes + MTRc * 32 * 2 + 2 * (MTRc * 1024 * 2)
                    + MTRc * 544 * 2 + 4096;
        if (need <= ws_size) { EC = ec; break; }
    }
    const int MT  = (EC + 127) / 128;
    const size_t MTR = (size_t)MT * 128;
    _Float16* e_in = (_Float16*)alloc(MTR * 32 * 2);    // [MT][1]
    _Float16* ping = (_Float16*)alloc(MTR * 1024 * 2);  // [MT][32]
    _Float16* pong = (_Float16*)alloc(MTR * 1024 * 2);  // [MT][32]
    _Float16* ninb = (_Float16*)alloc(MTR * 544 * 2);   // [MT][17]
    const int NCH = (EE + EC - 1) / EC;

    (void)hipMemsetAsync(W, 0, zeroBytes, stream);

    hipLaunchKernelGGL(k_u_r, dim3(1024), dim3(256), 0, stream, u, w_sel, b_sel, u_r);
    hipLaunchKernelGGL(k_graph_bias, GRID1(16 * 1024 * 64), dim3(256), 0, stream,
                       u_r, ew0, eb0, ub0, 1024, 275, 19);
    hipLaunchKernelGGL(k_graph_bias, GRID1(16 * 512 * 64), dim3(256), 0, stream,
                       u_r, mw0, mb0, ubm, 512, 777, 521);
    hipLaunchKernelGGL(k_gbe, GRID1(EE), dim3(256), 0, stream, row, batch, gbe);

    auto pack = [&](const float* w, _Float16* wh, int N, int Ksrc, int Kd, int mode) {
        hipLaunchKernelGGL(k_w2h_blk, GRID1(N * Kd), dim3(256), 0, stream, w, wh, N, Ksrc, Kd, mode);
    };
    pack(ew0, wh0, 1024, 275, 32, 1);
    pack(ew1, wh1, 1024, 1024, 1024, 0);
    pack(ew2, wh2, 1024, 1024, 1024, 0);
    pack(ew3, wh3, 1024, 1024, 1024, 0);
    pack(ew4, wh4, 512, 1024, 1024, 0);
    pack(nw0, whn0, 512, 521, 544, 2);
    pack(nw1, whn1, 512, 512, 512, 0);
    pack(mw0, whm0, 512, 777, 544, 2);

    hipLaunchKernelGGL(k_count, GRID1(EE), dim3(256), 0, stream, row, cnt);

    for (int ch = 0; ch < NCH; ++ch) {
        int e0 = ch * EC;
        int ec = EC; if (e0 + ec > EE) ec = EE - e0;
        hipLaunchKernelGGL(k_gather_edge_blk, GRID1((int)MTR * 4), dim3(256), 0, stream,
                           x, ea, row, col, e_in, e0, ec, (int)MTR);
        // l0: K=32, per-graph bias ub0
        gemmB0(stream, e_in, wh0, 1, ub0, 1024, gbe + e0, ping, 32, 0, ec, MT, 8, 1);
        gemmB0(stream, ping, wh1, 32, eb1, 0, nullptr, pong, 32, 0, ec, MT, 8, 1);
        gemmB0(stream, pong, wh2, 32, eb2, 0, nullptr, ping, 32, 0, ec, MT, 8, 1);
        gemmB0(stream, ping, wh3, 32, eb3, 0, nullptr, pong, 32, 0, ec, MT, 8, 1);
        // ew4 -> ninb (blocked, kt offset 1), no relu on edge_out
        gemmB0(stream, pong, wh4, 32, eb4, 0, nullptr, ninb, 17, 1, ec, MT, 4, 0);
        hipLaunchKernelGGL(k_gather_nin0, GRID1((int)MTR * 4), dim3(256), 0, stream,
                           x, col, ninb, e0, ec, (int)MTR);
        gemmB0(stream, ninb, whn0, 17, nb0, 0, nullptr, ping, 16, 0, ec, MT, 4, 1);
        // n1: fused COALESCED scatter-add into agg (mode 2)
        gemmB2(stream, ping, whn1, 16, nb1, row + e0, agg, ec, MT, 4, 1);
    }

    hipLaunchKernelGGL(k_gather_min, GRID1((int)(MTm * 128) * 68), dim3(256), 0, stream,
                       x, agg, cnt, m_in, MTm * 128);
    // m0: f32 row-major out, per-graph bias ubm (gbid = batch)
    gemmB1(stream, m_in, whm0, 17, ubm, 512, batch, h2, 512, NN, MTm, 4, 1);
    hipLaunchKernelGGL(k_final, dim3((NN + 3) / 4), dim3(256), 0, stream,
                       h2, mw1, mb1, (float*)d_out);
}

// Round 10
// 2140.582 us; speedup vs baseline: 1.2245x; 1.0162x over previous
//
#include <hip/hip_runtime.h>

// ---------------------------------------------------------------------------
// OGRENet GraphNet block — f16 MFMA with BLOCKED operand layout, BK=64.
// Blocked layout (f16): offset(m,k) = ((mt*KT + kt)*4 + kg)*1024 + r*8 + ko
//   mt=m>>7, r=m&127, kt=k>>5, kg=(k>>3)&3, ko=k&7.   (tile = 128x32 = 8KB)
// K-loop stages TWO kt-blocks (32KB LDS) per barrier pair -> half the
// vmcnt(0) barrier drains of the BK=32 m97 structure (the measured stall).
// Odd-KT leftover does one BK=32 step.  MODE is a template param (R8 lesson:
// runtime mode -> worst-case VGPR taxes all GEMMs).
//  mode 0: re-block C via 2-pass LDS transpose (f16, conflict-free)
//  mode 1: f32 row-major
//  mode 2: fused scatter-add, 4-pass f32 LDS transpose -> COALESCED atomics
// XCD swizzle: 8 column-blocks of one M-panel land on the same XCD.
// [R7 lesson: rocprof serialized replay overstates atomic kernels ~20x.]
// ---------------------------------------------------------------------------

#define NN 20000
#define EE 100000
#define BB 16

typedef _Float16 f16x8 __attribute__((ext_vector_type(8)));
typedef _Float16 f16x4 __attribute__((ext_vector_type(4)));
typedef float f32x4 __attribute__((ext_vector_type(4)));

__device__ __forceinline__ int clampi(int v, int hi) {
    return v < 0 ? 0 : (v >= hi ? hi - 1 : v);
}

__device__ __forceinline__ void gld_lds16(const void* g, void* l) {
    __builtin_amdgcn_global_load_lds(
        (const __attribute__((address_space(1))) unsigned int*)g,
        (__attribute__((address_space(3))) unsigned int*)l, 16, 0, 0);
}

// ------------------------- blocked f16 MFMA GEMM ---------------------------
template <int MODE>
__global__ __launch_bounds__(256) void gemm_blk(
    const _Float16* __restrict__ A,      // blocked [MT][KT]
    const _Float16* __restrict__ Wt,     // blocked [NT][KT]
    int KT,
    const float* __restrict__ bias, int ldbias, const int* __restrict__ gbid,
    void* __restrict__ C, int KTo, int ktOff,   // mode 0: blocked f16 out
    int ldc,                                    // mode 1: f32 row-major out
    const int* __restrict__ srow, float* __restrict__ agg,  // mode 2
    int M, int relu)
{
    __shared__ char smem[32768];   // staging 2x16KB | m0 tr 16.9KB | m2 trf 16.6KB
    _Float16* As = (_Float16*)smem;          // 8192 f16
    _Float16* Bs = As + 8192;

    const int tid  = threadIdx.x;
    const int lane = tid & 63;
    const int wid  = tid >> 6;
    const int wm = (wid & 1) << 6;
    const int wn = (wid >> 1) << 6;

    // XCD swizzle: panel p's column-blocks share f%8 (same XCD)
    const int nb = gridDim.x;
    const int MT = gridDim.y;
    int f = blockIdx.y * nb + blockIdx.x;
    const int MT8 = MT & ~7;
    int p, c;
    if (f < MT8 * nb) {
        c = (f >> 3) % nb;
        p = (f & 7) + 8 * ((f >> 3) / nb);
    } else {
        int g = f - MT8 * nb;
        p = MT8 + g / nb;
        c = g % nb;
    }

    f32x4 acc[4][4];
#pragma unroll
    for (int i = 0; i < 4; ++i)
#pragma unroll
        for (int j = 0; j < 4; ++j) acc[i][j] = (f32x4){0.f, 0.f, 0.f, 0.f};

    const _Float16* pA = A + (size_t)p * KT * 4096;
    const _Float16* pB = Wt + (size_t)c * KT * 4096;
    const int cb0 = wid * 64;         // chunk base, inst 0 (within 512-chunk half)
    const int cb1 = 256 + wid * 64;   // chunk base, inst 1
    const int kq  = (lane >> 4) * 128;
    const int l15 = lane & 15;
    const int l4  = (lane >> 4) << 2;

    // main loop: BK=64 (two kt blocks per barrier pair)
    int kt = 0;
    for (; kt + 2 <= KT; kt += 2) {
        __syncthreads();
        gld_lds16(pA + (size_t)(cb0 + lane) * 8,        As + cb0 * 8);
        gld_lds16(pA + (size_t)(cb1 + lane) * 8,        As + cb1 * 8);
        gld_lds16(pA + 4096 + (size_t)(cb0 + lane) * 8, As + 4096 + cb0 * 8);
        gld_lds16(pA + 4096 + (size_t)(cb1 + lane) * 8, As + 4096 + cb1 * 8);
        gld_lds16(pB + (size_t)(cb0 + lane) * 8,        Bs + cb0 * 8);
        gld_lds16(pB + (size_t)(cb1 + lane) * 8,        Bs + cb1 * 8);
        gld_lds16(pB + 4096 + (size_t)(cb0 + lane) * 8, Bs + 4096 + cb0 * 8);
        gld_lds16(pB + 4096 + (size_t)(cb1 + lane) * 8, Bs + 4096 + cb1 * 8);
        pA += 8192; pB += 8192;
        __syncthreads();

#pragma unroll
        for (int s = 0; s < 2; ++s) {
            f16x8 af[4], bf[4];
            const int sb = s * 4096;
#pragma unroll
            for (int i = 0; i < 4; ++i)
                af[i] = *(const f16x8*)(As + sb + (size_t)((kq + wm + i * 16 + l15) << 3));
#pragma unroll
            for (int j = 0; j < 4; ++j)
                bf[j] = *(const f16x8*)(Bs + sb + (size_t)((kq + wn + j * 16 + l15) << 3));
#pragma unroll
            for (int i = 0; i < 4; ++i)
#pragma unroll
                for (int j = 0; j < 4; ++j)
                    acc[i][j] = __builtin_amdgcn_mfma_f32_16x16x32_f16(af[i], bf[j], acc[i][j], 0, 0, 0);
        }
    }
    // leftover: BK=32
    if (kt < KT) {
        __syncthreads();
        gld_lds16(pA + (size_t)(cb0 + lane) * 8, As + cb0 * 8);
        gld_lds16(pA + (size_t)(cb1 + lane) * 8, As + cb1 * 8);
        gld_lds16(pB + (size_t)(cb0 + lane) * 8, Bs + cb0 * 8);
        gld_lds16(pB + (size_t)(cb1 + lane) * 8, Bs + cb1 * 8);
        __syncthreads();
        f16x8 af[4], bf[4];
#pragma unroll
        for (int i = 0; i < 4; ++i)
            af[i] = *(const f16x8*)(As + (size_t)((kq + wm + i * 16 + l15) << 3));
#pragma unroll
        for (int j = 0; j < 4; ++j)
            bf[j] = *(const f16x8*)(Bs + (size_t)((kq + wn + j * 16 + l15) << 3));
#pragma unroll
        for (int i = 0; i < 4; ++i)
#pragma unroll
            for (int j = 0; j < 4; ++j)
                acc[i][j] = __builtin_amdgcn_mfma_f32_16x16x32_f16(af[i], bf[j], acc[i][j], 0, 0, 0);
    }

    if (MODE == 0) {
        // re-block C through LDS, two passes of 64 rows (tr = [64][132] f16)
        _Float16* tr = (_Float16*)smem;
#pragma unroll
        for (int pass = 0; pass < 2; ++pass) {
            __syncthreads();
            if (wm == pass * 64) {
#pragma unroll
                for (int i = 0; i < 4; ++i) {
#pragma unroll
                    for (int v = 0; v < 4; ++v) {
                        const int lr = i * 16 + l4 + v;
                        const float* brow = bias;
                        if (gbid) {
                            int m = p * 128 + pass * 64 + lr;
                            if (m >= M) m = M - 1;
                            brow = bias + (size_t)clampi(gbid[m], BB) * ldbias;
                        }
#pragma unroll
                        for (int j = 0; j < 4; ++j) {
                            const int cc = wn + j * 16 + l15;
                            float val = acc[i][j][v] + brow[c * 128 + cc];
                            if (relu) val = fmaxf(val, 0.f);
                            tr[lr * 132 + cc] = (_Float16)val;
                        }
                    }
                }
            }
            __syncthreads();
#pragma unroll
            for (int it = 0; it < 4; ++it) {
                const int id = it * 256 + tid;
                const int r  = id & 63;
                const int cg = id >> 6;
                f16x4 lo = *(const f16x4*)(tr + r * 132 + cg * 8);
                f16x4 hi = *(const f16x4*)(tr + r * 132 + cg * 8 + 4);
                f16x8 v8;
#pragma unroll
                for (int t = 0; t < 4; ++t) { v8[t] = lo[t]; v8[t + 4] = hi[t]; }
                const int kti = ktOff + (c << 2) + (cg >> 2);
                const int gr  = pass * 64 + r;
                size_t o = (((size_t)p * KTo + kti) * 4 + (cg & 3)) * 1024 + (size_t)gr * 8;
                *(f16x8*)((_Float16*)C + o) = v8;
            }
        }
    } else if (MODE == 1) {
#pragma unroll
        for (int i = 0; i < 4; ++i) {
#pragma unroll
            for (int v = 0; v < 4; ++v) {
                const int m = p * 128 + wm + i * 16 + l4 + v;
                if (m >= M) continue;
                const float* brow = bias;
                if (gbid) brow = bias + (size_t)clampi(gbid[m], BB) * ldbias;
#pragma unroll
                for (int j = 0; j < 4; ++j) {
                    const int col = c * 128 + wn + j * 16 + l15;
                    float val = acc[i][j][v] + brow[col];
                    if (relu) val = fmaxf(val, 0.f);
                    ((float*)C)[(size_t)m * ldc + col] = val;
                }
            }
        }
    } else {
        // mode 2: fused coalesced scatter-add. 4 passes of 32 rows.
        float* trf = (float*)smem;   // [32][130] f32, 16640 B
#pragma unroll
        for (int pass = 0; pass < 4; ++pass) {
            __syncthreads();
            if (wm == ((pass >> 1) << 6)) {      // pass 0,1 -> wm 0; 2,3 -> wm 64
                const int i0 = (pass & 1) << 1;  // 0 or 2
#pragma unroll
                for (int ii = 0; ii < 2; ++ii) {
                    const int i = i0 + ii;
                    const int lr = ii * 16 + l4;
#pragma unroll
                    for (int v = 0; v < 4; ++v) {
#pragma unroll
                        for (int j = 0; j < 4; ++j) {
                            const int cc = wn + j * 16 + l15;
                            float val = acc[i][j][v] + bias[c * 128 + cc];
                            if (relu) val = fmaxf(val, 0.f);
                            trf[(lr + v) * 130 + cc] = val;
                        }
                    }
                }
            }
            __syncthreads();
            const int ebase = p * 128 + pass * 32;
#pragma unroll
            for (int it = 0; it < 16; ++it) {
                const int id = it * 256 + tid;   // 0..4095
                const int lr = id >> 7;          // 0..31
                const int colg = id & 127;
                const int el = ebase + lr;
                if (el < M) {
                    const int node = clampi(srow[el], NN);
                    atomicAdd(&agg[(size_t)node * 512 + c * 128 + colg],
                              trf[lr * 130 + colg]);
                }
            }
        }
    }
}

// ------------------------- helper kernels ----------------------------------

// fp32 w[N][Ksrc] -> blocked f16 [N/128][Kd/32] tiles.
// colmap mode: 0 plain (k<Ksrc), 1 e0 (k<19), 2 pack544 (k<9 | 32<=k<544 -> 9+(k-32))
__global__ void k_w2h_blk(const float* __restrict__ src, _Float16* __restrict__ dst,
                          int N, int Ksrc, int Kd, int mode)
{
    int t = blockIdx.x * blockDim.x + threadIdx.x;
    if (t >= N * Kd) return;
    int n = t / Kd, k = t - n * Kd;
    int sc = -1;
    if (mode == 0)      { if (k < Ksrc) sc = k; }
    else if (mode == 1) { if (k < 19) sc = k; }
    else                { if (k < 9) sc = k; else if (k >= 32 && k < 544) sc = 9 + (k - 32); }
    float v = (sc >= 0) ? src[(size_t)n * Ksrc + sc] : 0.f;
    int KT = Kd >> 5;
    int nt = n >> 7, r = n & 127, kt = k >> 5, kg = (k >> 3) & 3, ko = k & 7;
    dst[(((size_t)nt * KT + kt) * 4 + kg) * 1024 + (size_t)r * 8 + ko] = (_Float16)v;
}

// u_r[16,256] fp32
__global__ void k_u_r(const float* __restrict__ u, const float* __restrict__ w_sel,
                      const float* __restrict__ b_sel, float* __restrict__ u_r)
{
    int wave = (blockIdx.x * 256 + threadIdx.x) >> 6;
    int lane = threadIdx.x & 63;
    int b = wave >> 8, n = wave & 255;
    const float4* u4 = (const float4*)(u + (size_t)b * 4096);
    const float4* w4 = (const float4*)(w_sel + (size_t)n * 4096);
    float s = 0.f;
    for (int i = lane; i < 1024; i += 64) {
        float4 a = u4[i], c = w4[i];
        s += a.x * c.x + a.y * c.y + a.z * c.z + a.w * c.w;
    }
    for (int off = 32; off; off >>= 1) s += __shfl_down(s, off);
    if (lane == 0) u_r[b * 256 + n] = s + b_sel[n];
}

// ub[16][Nout] = u_r @ w[:, koff:koff+256]^T + b
__global__ void k_graph_bias(const float* __restrict__ u_r, const float* __restrict__ w,
                             const float* __restrict__ b, float* __restrict__ ub,
                             int Nout, int Ksrc, int koff)
{
    int wave = (blockIdx.x * 256 + threadIdx.x) >> 6;
    int lane = threadIdx.x & 63;
    if (wave >= 16 * Nout) return;
    int g = wave / Nout, n = wave - g * Nout;
    const float* ur = u_r + (size_t)g * 256;
    const float* wr = w + (size_t)n * Ksrc + koff;
    float s = 0.f;
#pragma unroll
    for (int i = 0; i < 4; ++i) s += ur[lane * 4 + i] * wr[lane * 4 + i];
    for (int off = 32; off; off >>= 1) s += __shfl_down(s, off);
    if (lane == 0) ub[(size_t)g * Nout + n] = s + b[n];
}

__global__ void k_gbe(const int* __restrict__ row, const int* __restrict__ batch,
                      int* __restrict__ gbe)
{
    int e = blockIdx.x * blockDim.x + threadIdx.x;
    if (e < EE) gbe[e] = clampi(batch[clampi(row[e], NN)], BB);
}

// e_in blocked [MT][1]: cols = [x[row](9) | x[col](9) | ea | 0..]
__global__ void k_gather_edge_blk(const float* __restrict__ x, const float* __restrict__ ea,
                                  const int* __restrict__ row, const int* __restrict__ col,
                                  _Float16* __restrict__ dst, int e0, int ec, int MTR)
{
    int t = blockIdx.x * blockDim.x + threadIdx.x;
    if (t >= MTR * 4) return;
    int r = t >> 2, kg = t & 3;
    int e = e0 + r; int emax = e0 + ec - 1;
    if (e > emax) e = emax;
    int ri = clampi(row[e], NN), ci = clampi(col[e], NN);
    f16x8 v;
#pragma unroll
    for (int j = 0; j < 8; ++j) {
        int cc = kg * 8 + j;
        float fv = 0.f;
        if (cc < 9)       fv = x[(size_t)ri * 9 + cc];
        else if (cc < 18) fv = x[(size_t)ci * 9 + (cc - 9)];
        else if (cc == 18) fv = ea[e];
        v[j] = (_Float16)fv;
    }
    *(f16x8*)(dst + (size_t)(r >> 7) * 4096 + (size_t)kg * 1024 + (size_t)(r & 127) * 8) = v;
}

// ninb kt0 (x[col] | pad) blocked; kt1..16 written by ew4's epilogue
__global__ void k_gather_nin0(const float* __restrict__ x, const int* __restrict__ col,
                              _Float16* __restrict__ dst, int e0, int ec, int MTR)
{
    int t = blockIdx.x * blockDim.x + threadIdx.x;
    if (t >= MTR * 4) return;
    int r = t >> 2, kg = t & 3;
    int e = e0 + r; int emax = e0 + ec - 1;
    if (e > emax) e = emax;
    int ci = clampi(col[e], NN);
    f16x8 v = (f16x8)(_Float16)0.f;
#pragma unroll
    for (int j = 0; j < 8; ++j) {
        int cc = kg * 8 + j;
        if (cc < 9) v[j] = (_Float16)x[(size_t)ci * 9 + cc];
    }
    *(f16x8*)(dst + ((size_t)(r >> 7) * 17) * 4096 + (size_t)kg * 1024 + (size_t)(r & 127) * 8) = v;
}

// m_in blocked [MTm][17]: cols = [x(9)|pad23 | agg/cnt(512)]
__global__ void k_gather_min(const float* __restrict__ x, const float* __restrict__ agg,
                             const float* __restrict__ cnt, _Float16* __restrict__ dst, int MTR)
{
    int t = blockIdx.x * blockDim.x + threadIdx.x;
    if (t >= MTR * 68) return;
    int r = t / 68, q = t - r * 68;
    int kt = q >> 2, kg = q & 3;
    int n = r < NN ? r : NN - 1;
    f16x8 v = (f16x8)(_Float16)0.f;
    if (kt == 0) {
#pragma unroll
        for (int j = 0; j < 8; ++j) {
            int cc = kg * 8 + j;
            if (cc < 9) v[j] = (_Float16)x[(size_t)n * 9 + cc];
        }
    } else {
        float inv = 1.f / fmaxf(cnt[n], 1.f);
        int cbase = (kt - 1) * 32 + kg * 8;
        const float4* ap = (const float4*)(agg + (size_t)n * 512 + cbase);
        float4 a0 = ap[0], a1 = ap[1];
        v[0] = (_Float16)(a0.x * inv); v[1] = (_Float16)(a0.y * inv);
        v[2] = (_Float16)(a0.z * inv); v[3] = (_Float16)(a0.w * inv);
        v[4] = (_Float16)(a1.x * inv); v[5] = (_Float16)(a1.y * inv);
        v[6] = (_Float16)(a1.z * inv); v[7] = (_Float16)(a1.w * inv);
    }
    *(f16x8*)(dst + ((size_t)(r >> 7) * 17 + kt) * 4096 + (size_t)kg * 1024 + (size_t)(r & 127) * 8) = v;
}

__global__ void k_count(const int* __restrict__ row, float* __restrict__ cnt)
{
    int e = blockIdx.x * blockDim.x + threadIdx.x;
    if (e < EE) atomicAdd(&cnt[clampi(row[e], NN)], 1.f);
}

// out[n] = h2[n,:] . mw1 + mb1
__global__ void k_final(const float* __restrict__ h2, const float* __restrict__ mw1,
                        const float* __restrict__ mb1, float* __restrict__ out)
{
    int wave = (blockIdx.x * 256 + threadIdx.x) >> 6;
    int lane = threadIdx.x & 63;
    if (wave >= NN) return;
    const float4* h4 = (const float4*)(h2 + (size_t)wave * 512);
    const float4* w4 = (const float4*)mw1;
    float s = 0.f;
#pragma unroll
    for (int i = 0; i < 2; ++i) {
        int f = lane * 2 + i;
        float4 a = h4[f], b = w4[f];
        s += a.x * b.x + a.y * b.y + a.z * b.z + a.w * b.w;
    }
    for (int off = 32; off; off >>= 1) s += __shfl_down(s, off);
    if (lane == 0) out[wave] = s + mb1[0];
}

// ------------------------------- host --------------------------------------

#define GRID1(n) dim3(((n) + 255) / 256)

static inline void gemmB0(hipStream_t s, const _Float16* A, const _Float16* Wt, int KT,
                          const float* bias, int ldbias, const int* gbid,
                          void* C, int KTo, int ktOff,
                          int M, int MT, int NT, int relu)
{
    hipLaunchKernelGGL(gemm_blk<0>, dim3(NT, MT), dim3(256), 0, s,
                       A, Wt, KT, bias, ldbias, gbid, C, KTo, ktOff, 0,
                       nullptr, nullptr, M, relu);
}
static inline void gemmB1(hipStream_t s, const _Float16* A, const _Float16* Wt, int KT,
                          const float* bias, int ldbias, const int* gbid,
                          void* C, int ldc, int M, int MT, int NT, int relu)
{
    hipLaunchKernelGGL(gemm_blk<1>, dim3(NT, MT), dim3(256), 0, s,
                       A, Wt, KT, bias, ldbias, gbid, C, 0, 0, ldc,
                       nullptr, nullptr, M, relu);
}
static inline void gemmB2(hipStream_t s, const _Float16* A, const _Float16* Wt, int KT,
                          const float* bias, const int* srow, float* agg,
                          int M, int MT, int NT, int relu)
{
    hipLaunchKernelGGL(gemm_blk<2>, dim3(NT, MT), dim3(256), 0, s,
                       A, Wt, KT, bias, 0, nullptr, nullptr, 0, 0, 0,
                       srow, agg, M, relu);
}

extern "C" void kernel_launch(void* const* d_in, const int* in_sizes, int n_in,
                              void* d_out, int out_size, void* d_ws, size_t ws_size,
                              hipStream_t stream)
{
    const float* x     = (const float*)d_in[0];
    const int*   ei    = (const int*)d_in[1];
    const float* ea    = (const float*)d_in[2];
    const float* u     = (const float*)d_in[3];
    const int*   batch = (const int*)d_in[4];
    const float* w_sel = (const float*)d_in[5];
    const float* b_sel = (const float*)d_in[6];
    const float* ew0 = (const float*)d_in[7];   const float* eb0 = (const float*)d_in[8];
    const float* ew1 = (const float*)d_in[9];   const float* eb1 = (const float*)d_in[10];
    const float* ew2 = (const float*)d_in[11];  const float* eb2 = (const float*)d_in[12];
    const float* ew3 = (const float*)d_in[13];  const float* eb3 = (const float*)d_in[14];
    const float* ew4 = (const float*)d_in[15];  const float* eb4 = (const float*)d_in[16];
    const float* nw0 = (const float*)d_in[17];  const float* nb0 = (const float*)d_in[18];
    const float* nw1 = (const float*)d_in[19];  const float* nb1 = (const float*)d_in[20];
    const float* mw0 = (const float*)d_in[21];  const float* mb0 = (const float*)d_in[22];
    const float* mw1 = (const float*)d_in[23];  const float* mb1 = (const float*)d_in[24];

    const int* row = ei;
    const int* col = ei + EE;

    char* W = (char*)d_ws;
    size_t off = 0;
    auto alloc = [&](size_t bytes) -> char* {
        char* p = W + off;
        off = (off + bytes + 255) & ~(size_t)255;
        return p;
    };
    float*    cnt  = (float*)alloc(20000 * 4);
    float*    agg  = (float*)alloc((size_t)NN * 512 * 4);
    const size_t zeroBytes = off;
    float*    u_r  = (float*)alloc(16 * 256 * 4);
    float*    ub0  = (float*)alloc(16 * 1024 * 4);
    float*    ubm  = (float*)alloc(16 * 512 * 4);
    int*      gbe  = (int*)alloc((size_t)EE * 4);
    _Float16* wh0  = (_Float16*)alloc((size_t)8 * 1 * 4096 * 2);
    _Float16* wh1  = (_Float16*)alloc((size_t)8 * 32 * 4096 * 2);
    _Float16* wh2  = (_Float16*)alloc((size_t)8 * 32 * 4096 * 2);
    _Float16* wh3  = (_Float16*)alloc((size_t)8 * 32 * 4096 * 2);
    _Float16* wh4  = (_Float16*)alloc((size_t)4 * 32 * 4096 * 2);
    _Float16* whn0 = (_Float16*)alloc((size_t)4 * 17 * 4096 * 2);
    _Float16* whn1 = (_Float16*)alloc((size_t)4 * 16 * 4096 * 2);
    _Float16* whm0 = (_Float16*)alloc((size_t)4 * 17 * 4096 * 2);
    const int MTm = (NN + 127) / 128;           // 157
    float*    h2   = (float*)alloc((size_t)NN * 512 * 4);
    _Float16* m_in = (_Float16*)alloc((size_t)MTm * 17 * 4096 * 2);
    const size_t fixedBytes = off;

    // choose edge chunk (depends only on ws_size -> capture-safe).
    static const int ecOpts[] = {25000, 12500, 10000, 5000};
    int EC = 5000;
    for (int i = 0; i < 4; ++i) {
        int ec = ecOpts[i];
        size_t MTRc = (size_t)((ec + 127) / 128) * 128;
        size_t need = fixedBytes + MTRc * 32 * 2 + 2 * (MTRc * 1024 * 2)
                    + MTRc * 544 * 2 + 4096;
        if (need <= ws_size) { EC = ec; break; }
    }
    const int MT  = (EC + 127) / 128;
    const size_t MTR = (size_t)MT * 128;
    _Float16* e_in = (_Float16*)alloc(MTR * 32 * 2);    // [MT][1]
    _Float16* ping = (_Float16*)alloc(MTR * 1024 * 2);  // [MT][32]
    _Float16* pong = (_Float16*)alloc(MTR * 1024 * 2);  // [MT][32]
    _Float16* ninb = (_Float16*)alloc(MTR * 544 * 2);   // [MT][17]
    const int NCH = (EE + EC - 1) / EC;

    (void)hipMemsetAsync(W, 0, zeroBytes, stream);

    hipLaunchKernelGGL(k_u_r, dim3(1024), dim3(256), 0, stream, u, w_sel, b_sel, u_r);
    hipLaunchKernelGGL(k_graph_bias, GRID1(16 * 1024 * 64), dim3(256), 0, stream,
                       u_r, ew0, eb0, ub0, 1024, 275, 19);
    hipLaunchKernelGGL(k_graph_bias, GRID1(16 * 512 * 64), dim3(256), 0, stream,
                       u_r, mw0, mb0, ubm, 512, 777, 521);
    hipLaunchKernelGGL(k_gbe, GRID1(EE), dim3(256), 0, stream, row, batch, gbe);

    auto pack = [&](const float* w, _Float16* wh, int N, int Ksrc, int Kd, int mode) {
        hipLaunchKernelGGL(k_w2h_blk, GRID1(N * Kd), dim3(256), 0, stream, w, wh, N, Ksrc, Kd, mode);
    };
    pack(ew0, wh0, 1024, 275, 32, 1);
    pack(ew1, wh1, 1024, 1024, 1024, 0);
    pack(ew2, wh2, 1024, 1024, 1024, 0);
    pack(ew3, wh3, 1024, 1024, 1024, 0);
    pack(ew4, wh4, 512, 1024, 1024, 0);
    pack(nw0, whn0, 512, 521, 544, 2);
    pack(nw1, whn1, 512, 512, 512, 0);
    pack(mw0, whm0, 512, 777, 544, 2);

    hipLaunchKernelGGL(k_count, GRID1(EE), dim3(256), 0, stream, row, cnt);

    for (int ch = 0; ch < NCH; ++ch) {
        int e0 = ch * EC;
        int ec = EC; if (e0 + ec > EE) ec = EE - e0;
        hipLaunchKernelGGL(k_gather_edge_blk, GRID1((int)MTR * 4), dim3(256), 0, stream,
                           x, ea, row, col, e_in, e0, ec, (int)MTR);
        // l0: K=32, per-graph bias ub0
        gemmB0(stream, e_in, wh0, 1, ub0, 1024, gbe + e0, ping, 32, 0, ec, MT, 8, 1);
        gemmB0(stream, ping, wh1, 32, eb1, 0, nullptr, pong, 32, 0, ec, MT, 8, 1);
        gemmB0(stream, pong, wh2, 32, eb2, 0, nullptr, ping, 32, 0, ec, MT, 8, 1);
        gemmB0(stream, ping, wh3, 32, eb3, 0, nullptr, pong, 32, 0, ec, MT, 8, 1);
        // ew4 -> ninb (blocked, kt offset 1), no relu on edge_out
        gemmB0(stream, pong, wh4, 32, eb4, 0, nullptr, ninb, 17, 1, ec, MT, 4, 0);
        hipLaunchKernelGGL(k_gather_nin0, GRID1((int)MTR * 4), dim3(256), 0, stream,
                           x, col, ninb, e0, ec, (int)MTR);
        gemmB0(stream, ninb, whn0, 17, nb0, 0, nullptr, ping, 16, 0, ec, MT, 4, 1);
        // n1: fused COALESCED scatter-add into agg (mode 2)
        gemmB2(stream, ping, whn1, 16, nb1, row + e0, agg, ec, MT, 4, 1);
    }

    hipLaunchKernelGGL(k_gather_min, GRID1((int)(MTm * 128) * 68), dim3(256), 0, stream,
                       x, agg, cnt, m_in, MTm * 128);
    // m0: f32 row-major out, per-graph bias ubm (gbid = batch)
    gemmB1(stream, m_in, whm0, 17, ubm, 512, batch, h2, 512, NN, MTm, 4, 1);
    hipLaunchKernelGGL(k_final, dim3((NN + 3) / 4), dim3(256), 0, stream,
                       h2, mw1, mb1, (float*)d_out);
}

// Round 11
// 1543.875 us; speedup vs baseline: 1.6977x; 1.3865x over previous
//
#include <hip/hip_runtime.h>

// ---------------------------------------------------------------------------
// OGRENet GraphNet block — f16 MFMA with BLOCKED operand layout, BK=64.
// Blocked layout (f16): offset(m,k) = ((mt*KT + kt)*4 + kg)*1024 + r*8 + ko
//   mt=m>>7, r=m&127, kt=k>>5, kg=(k>>3)&3, ko=k&7.   (tile = 128x32 = 8KB)
// __launch_bounds__(256, 4): cap VGPR+AGPR at 128/thread -> 4 blocks/CU
// (R10: 156 regs -> 3 blocks/CU, occupancy 17%, latency-bound at reg limit).
// MODE is a template param (R8 lesson: runtime mode taxes all GEMMs).
//  mode 0: re-block C via 2-pass LDS transpose (f16, conflict-free)
//  mode 1: f32 row-major
//  mode 2: fused scatter-add, 4-pass f32 LDS transpose -> COALESCED atomics
// XCD swizzle: 8 column-blocks of one M-panel land on the same XCD.
// [R7 lesson: rocprof serialized replay overstates atomic kernels ~20x.]
// [ws_size ~250-300MB (R3-R7 archaeology) -> EC=25000 is the max chunk.]
// ---------------------------------------------------------------------------

#define NN 20000
#define EE 100000
#define BB 16

typedef _Float16 f16x8 __attribute__((ext_vector_type(8)));
typedef _Float16 f16x4 __attribute__((ext_vector_type(4)));
typedef float f32x4 __attribute__((ext_vector_type(4)));

__device__ __forceinline__ int clampi(int v, int hi) {
    return v < 0 ? 0 : (v >= hi ? hi - 1 : v);
}

__device__ __forceinline__ void gld_lds16(const void* g, void* l) {
    __builtin_amdgcn_global_load_lds(
        (const __attribute__((address_space(1))) unsigned int*)g,
        (__attribute__((address_space(3))) unsigned int*)l, 16, 0, 0);
}

// ------------------------- blocked f16 MFMA GEMM ---------------------------
template <int MODE>
__global__ __launch_bounds__(256, 4) void gemm_blk(
    const _Float16* __restrict__ A,      // blocked [MT][KT]
    const _Float16* __restrict__ Wt,     // blocked [NT][KT]
    int KT,
    const float* __restrict__ bias, int ldbias, const int* __restrict__ gbid,
    void* __restrict__ C, int KTo, int ktOff,   // mode 0: blocked f16 out
    int ldc,                                    // mode 1: f32 row-major out
    const int* __restrict__ srow, float* __restrict__ agg,  // mode 2
    int M, int relu)
{
    __shared__ char smem[32768];   // staging 2x16KB | m0 tr 16.9KB | m2 trf 16.6KB
    _Float16* As = (_Float16*)smem;          // 8192 f16
    _Float16* Bs = As + 8192;

    const int tid  = threadIdx.x;
    const int lane = tid & 63;
    const int wid  = tid >> 6;
    const int wm = (wid & 1) << 6;
    const int wn = (wid >> 1) << 6;

    // XCD swizzle: panel p's column-blocks share f%8 (same XCD)
    const int nb = gridDim.x;
    const int MT = gridDim.y;
    int f = blockIdx.y * nb + blockIdx.x;
    const int MT8 = MT & ~7;
    int p, c;
    if (f < MT8 * nb) {
        c = (f >> 3) % nb;
        p = (f & 7) + 8 * ((f >> 3) / nb);
    } else {
        int g = f - MT8 * nb;
        p = MT8 + g / nb;
        c = g % nb;
    }

    f32x4 acc[4][4];
#pragma unroll
    for (int i = 0; i < 4; ++i)
#pragma unroll
        for (int j = 0; j < 4; ++j) acc[i][j] = (f32x4){0.f, 0.f, 0.f, 0.f};

    const _Float16* pA = A + (size_t)p * KT * 4096;
    const _Float16* pB = Wt + (size_t)c * KT * 4096;
    const int cb0 = wid * 64;         // chunk base, inst 0 (within 512-chunk half)
    const int cb1 = 256 + wid * 64;   // chunk base, inst 1
    const int kq  = (lane >> 4) * 128;
    const int l15 = lane & 15;
    const int l4  = (lane >> 4) << 2;

    // main loop: BK=64 (two kt blocks per barrier pair)
    int kt = 0;
    for (; kt + 2 <= KT; kt += 2) {
        __syncthreads();
        gld_lds16(pA + (size_t)(cb0 + lane) * 8,        As + cb0 * 8);
        gld_lds16(pA + (size_t)(cb1 + lane) * 8,        As + cb1 * 8);
        gld_lds16(pA + 4096 + (size_t)(cb0 + lane) * 8, As + 4096 + cb0 * 8);
        gld_lds16(pA + 4096 + (size_t)(cb1 + lane) * 8, As + 4096 + cb1 * 8);
        gld_lds16(pB + (size_t)(cb0 + lane) * 8,        Bs + cb0 * 8);
        gld_lds16(pB + (size_t)(cb1 + lane) * 8,        Bs + cb1 * 8);
        gld_lds16(pB + 4096 + (size_t)(cb0 + lane) * 8, Bs + 4096 + cb0 * 8);
        gld_lds16(pB + 4096 + (size_t)(cb1 + lane) * 8, Bs + 4096 + cb1 * 8);
        pA += 8192; pB += 8192;
        __syncthreads();

#pragma unroll
        for (int s = 0; s < 2; ++s) {
            f16x8 af[4], bf[4];
            const int sb = s * 4096;
#pragma unroll
            for (int i = 0; i < 4; ++i)
                af[i] = *(const f16x8*)(As + sb + (size_t)((kq + wm + i * 16 + l15) << 3));
#pragma unroll
            for (int j = 0; j < 4; ++j)
                bf[j] = *(const f16x8*)(Bs + sb + (size_t)((kq + wn + j * 16 + l15) << 3));
#pragma unroll
            for (int i = 0; i < 4; ++i)
#pragma unroll
                for (int j = 0; j < 4; ++j)
                    acc[i][j] = __builtin_amdgcn_mfma_f32_16x16x32_f16(af[i], bf[j], acc[i][j], 0, 0, 0);
        }
    }
    // leftover: BK=32
    if (kt < KT) {
        __syncthreads();
        gld_lds16(pA + (size_t)(cb0 + lane) * 8, As + cb0 * 8);
        gld_lds16(pA + (size_t)(cb1 + lane) * 8, As + cb1 * 8);
        gld_lds16(pB + (size_t)(cb0 + lane) * 8, Bs + cb0 * 8);
        gld_lds16(pB + (size_t)(cb1 + lane) * 8, Bs + cb1 * 8);
        __syncthreads();
        f16x8 af[4], bf[4];
#pragma unroll
        for (int i = 0; i < 4; ++i)
            af[i] = *(const f16x8*)(As + (size_t)((kq + wm + i * 16 + l15) << 3));
#pragma unroll
        for (int j = 0; j < 4; ++j)
            bf[j] = *(const f16x8*)(Bs + (size_t)((kq + wn + j * 16 + l15) << 3));
#pragma unroll
        for (int i = 0; i < 4; ++i)
#pragma unroll
            for (int j = 0; j < 4; ++j)
                acc[i][j] = __builtin_amdgcn_mfma_f32_16x16x32_f16(af[i], bf[j], acc[i][j], 0, 0, 0);
    }

    if (MODE == 0) {
        // re-block C through LDS, two passes of 64 rows (tr = [64][132] f16)
        _Float16* tr = (_Float16*)smem;
#pragma unroll
        for (int pass = 0; pass < 2; ++pass) {
            __syncthreads();
            if (wm == pass * 64) {
#pragma unroll
                for (int i = 0; i < 4; ++i) {
#pragma unroll
                    for (int v = 0; v < 4; ++v) {
                        const int lr = i * 16 + l4 + v;
                        const float* brow = bias;
                        if (gbid) {
                            int m = p * 128 + pass * 64 + lr;
                            if (m >= M) m = M - 1;
                            brow = bias + (size_t)clampi(gbid[m], BB) * ldbias;
                        }
#pragma unroll
                        for (int j = 0; j < 4; ++j) {
                            const int cc = wn + j * 16 + l15;
                            float val = acc[i][j][v] + brow[c * 128 + cc];
                            if (relu) val = fmaxf(val, 0.f);
                            tr[lr * 132 + cc] = (_Float16)val;
                        }
                    }
                }
            }
            __syncthreads();
#pragma unroll
            for (int it = 0; it < 4; ++it) {
                const int id = it * 256 + tid;
                const int r  = id & 63;
                const int cg = id >> 6;
                f16x4 lo = *(const f16x4*)(tr + r * 132 + cg * 8);
                f16x4 hi = *(const f16x4*)(tr + r * 132 + cg * 8 + 4);
                f16x8 v8;
#pragma unroll
                for (int t = 0; t < 4; ++t) { v8[t] = lo[t]; v8[t + 4] = hi[t]; }
                const int kti = ktOff + (c << 2) + (cg >> 2);
                const int gr  = pass * 64 + r;
                size_t o = (((size_t)p * KTo + kti) * 4 + (cg & 3)) * 1024 + (size_t)gr * 8;
                *(f16x8*)((_Float16*)C + o) = v8;
            }
        }
    } else if (MODE == 1) {
#pragma unroll
        for (int i = 0; i < 4; ++i) {
#pragma unroll
            for (int v = 0; v < 4; ++v) {
                const int m = p * 128 + wm + i * 16 + l4 + v;
                if (m >= M) continue;
                const float* brow = bias;
                if (gbid) brow = bias + (size_t)clampi(gbid[m], BB) * ldbias;
#pragma unroll
                for (int j = 0; j < 4; ++j) {
                    const int col = c * 128 + wn + j * 16 + l15;
                    float val = acc[i][j][v] + brow[col];
                    if (relu) val = fmaxf(val, 0.f);
                    ((float*)C)[(size_t)m * ldc + col] = val;
                }
            }
        }
    } else {
        // mode 2: fused coalesced scatter-add. 4 passes of 32 rows.
        float* trf = (float*)smem;   // [32][130] f32, 16640 B
#pragma unroll
        for (int pass = 0; pass < 4; ++pass) {
            __syncthreads();
            if (wm == ((pass >> 1) << 6)) {      // pass 0,1 -> wm 0; 2,3 -> wm 64
                const int i0 = (pass & 1) << 1;  // 0 or 2
#pragma unroll
                for (int ii = 0; ii < 2; ++ii) {
                    const int i = i0 + ii;
                    const int lr = ii * 16 + l4;
#pragma unroll
                    for (int v = 0; v < 4; ++v) {
#pragma unroll
                        for (int j = 0; j < 4; ++j) {
                            const int cc = wn + j * 16 + l15;
                            float val = acc[i][j][v] + bias[c * 128 + cc];
                            if (relu) val = fmaxf(val, 0.f);
                            trf[(lr + v) * 130 + cc] = val;
                        }
                    }
                }
            }
            __syncthreads();
            const int ebase = p * 128 + pass * 32;
#pragma unroll
            for (int it = 0; it < 16; ++it) {
                const int id = it * 256 + tid;   // 0..4095
                const int lr = id >> 7;          // 0..31
                const int colg = id & 127;
                const int el = ebase + lr;
                if (el < M) {
                    const int node = clampi(srow[el], NN);
                    atomicAdd(&agg[(size_t)node * 512 + c * 128 + colg],
                              trf[lr * 130 + colg]);
                }
            }
        }
    }
}

// ------------------------- helper kernels ----------------------------------

// fp32 w[N][Ksrc] -> blocked f16 [N/128][Kd/32] tiles.
// colmap mode: 0 plain (k<Ksrc), 1 e0 (k<19), 2 pack544 (k<9 | 32<=k<544 -> 9+(k-32))
__global__ void k_w2h_blk(const float* __restrict__ src, _Float16* __restrict__ dst,
                          int N, int Ksrc, int Kd, int mode)
{
    int t = blockIdx.x * blockDim.x + threadIdx.x;
    if (t >= N * Kd) return;
    int n = t / Kd, k = t - n * Kd;
    int sc = -1;
    if (mode == 0)      { if (k < Ksrc) sc = k; }
    else if (mode == 1) { if (k < 19) sc = k; }
    else                { if (k < 9) sc = k; else if (k >= 32 && k < 544) sc = 9 + (k - 32); }
    float v = (sc >= 0) ? src[(size_t)n * Ksrc + sc] : 0.f;
    int KT = Kd >> 5;
    int nt = n >> 7, r = n & 127, kt = k >> 5, kg = (k >> 3) & 3, ko = k & 7;
    dst[(((size_t)nt * KT + kt) * 4 + kg) * 1024 + (size_t)r * 8 + ko] = (_Float16)v;
}

// u_r[16,256] fp32
__global__ void k_u_r(const float* __restrict__ u, const float* __restrict__ w_sel,
                      const float* __restrict__ b_sel, float* __restrict__ u_r)
{
    int wave = (blockIdx.x * 256 + threadIdx.x) >> 6;
    int lane = threadIdx.x & 63;
    int b = wave >> 8, n = wave & 255;
    const float4* u4 = (const float4*)(u + (size_t)b * 4096);
    const float4* w4 = (const float4*)(w_sel + (size_t)n * 4096);
    float s = 0.f;
    for (int i = lane; i < 1024; i += 64) {
        float4 a = u4[i], c = w4[i];
        s += a.x * c.x + a.y * c.y + a.z * c.z + a.w * c.w;
    }
    for (int off = 32; off; off >>= 1) s += __shfl_down(s, off);
    if (lane == 0) u_r[b * 256 + n] = s + b_sel[n];
}

// ub[16][Nout] = u_r @ w[:, koff:koff+256]^T + b
__global__ void k_graph_bias(const float* __restrict__ u_r, const float* __restrict__ w,
                             const float* __restrict__ b, float* __restrict__ ub,
                             int Nout, int Ksrc, int koff)
{
    int wave = (blockIdx.x * 256 + threadIdx.x) >> 6;
    int lane = threadIdx.x & 63;
    if (wave >= 16 * Nout) return;
    int g = wave / Nout, n = wave - g * Nout;
    const float* ur = u_r + (size_t)g * 256;
    const float* wr = w + (size_t)n * Ksrc + koff;
    float s = 0.f;
#pragma unroll
    for (int i = 0; i < 4; ++i) s += ur[lane * 4 + i] * wr[lane * 4 + i];
    for (int off = 32; off; off >>= 1) s += __shfl_down(s, off);
    if (lane == 0) ub[(size_t)g * Nout + n] = s + b[n];
}

__global__ void k_gbe(const int* __restrict__ row, const int* __restrict__ batch,
                      int* __restrict__ gbe)
{
    int e = blockIdx.x * blockDim.x + threadIdx.x;
    if (e < EE) gbe[e] = clampi(batch[clampi(row[e], NN)], BB);
}

// e_in blocked [MT][1]: cols = [x[row](9) | x[col](9) | ea | 0..]
__global__ void k_gather_edge_blk(const float* __restrict__ x, const float* __restrict__ ea,
                                  const int* __restrict__ row, const int* __restrict__ col,
                                  _Float16* __restrict__ dst, int e0, int ec, int MTR)
{
    int t = blockIdx.x * blockDim.x + threadIdx.x;
    if (t >= MTR * 4) return;
    int r = t >> 2, kg = t & 3;
    int e = e0 + r; int emax = e0 + ec - 1;
    if (e > emax) e = emax;
    int ri = clampi(row[e], NN), ci = clampi(col[e], NN);
    f16x8 v;
#pragma unroll
    for (int j = 0; j < 8; ++j) {
        int cc = kg * 8 + j;
        float fv = 0.f;
        if (cc < 9)       fv = x[(size_t)ri * 9 + cc];
        else if (cc < 18) fv = x[(size_t)ci * 9 + (cc - 9)];
        else if (cc == 18) fv = ea[e];
        v[j] = (_Float16)fv;
    }
    *(f16x8*)(dst + (size_t)(r >> 7) * 4096 + (size_t)kg * 1024 + (size_t)(r & 127) * 8) = v;
}

// ninb kt0 (x[col] | pad) blocked; kt1..16 written by ew4's epilogue
__global__ void k_gather_nin0(const float* __restrict__ x, const int* __restrict__ col,
                              _Float16* __restrict__ dst, int e0, int ec, int MTR)
{
    int t = blockIdx.x * blockDim.x + threadIdx.x;
    if (t >= MTR * 4) return;
    int r = t >> 2, kg = t & 3;
    int e = e0 + r; int emax = e0 + ec - 1;
    if (e > emax) e = emax;
    int ci = clampi(col[e], NN);
    f16x8 v = (f16x8)(_Float16)0.f;
#pragma unroll
    for (int j = 0; j < 8; ++j) {
        int cc = kg * 8 + j;
        if (cc < 9) v[j] = (_Float16)x[(size_t)ci * 9 + cc];
    }
    *(f16x8*)(dst + ((size_t)(r >> 7) * 17) * 4096 + (size_t)kg * 1024 + (size_t)(r & 127) * 8) = v;
}

// m_in blocked [MTm][17]: cols = [x(9)|pad23 | agg/cnt(512)]
__global__ void k_gather_min(const float* __restrict__ x, const float* __restrict__ agg,
                             const float* __restrict__ cnt, _Float16* __restrict__ dst, int MTR)
{
    int t = blockIdx.x * blockDim.x + threadIdx.x;
    if (t >= MTR * 68) return;
    int r = t / 68, q = t - r * 68;
    int kt = q >> 2, kg = q & 3;
    int n = r < NN ? r : NN - 1;
    f16x8 v = (f16x8)(_Float16)0.f;
    if (kt == 0) {
#pragma unroll
        for (int j = 0; j < 8; ++j) {
            int cc = kg * 8 + j;
            if (cc < 9) v[j] = (_Float16)x[(size_t)n * 9 + cc];
        }
    } else {
        float inv = 1.f / fmaxf(cnt[n], 1.f);
        int cbase = (kt - 1) * 32 + kg * 8;
        const float4* ap = (const float4*)(agg + (size_t)n * 512 + cbase);
        float4 a0 = ap[0], a1 = ap[1];
        v[0] = (_Float16)(a0.x * inv); v[1] = (_Float16)(a0.y * inv);
        v[2] = (_Float16)(a0.z * inv); v[3] = (_Float16)(a0.w * inv);
        v[4] = (_Float16)(a1.x * inv); v[5] = (_Float16)(a1.y * inv);
        v[6] = (_Float16)(a1.z * inv); v[7] = (_Float16)(a1.w * inv);
    }
    *(f16x8*)(dst + ((size_t)(r >> 7) * 17 + kt) * 4096 + (size_t)kg * 1024 + (size_t)(r & 127) * 8) = v;
}

__global__ void k_count(const int* __restrict__ row, float* __restrict__ cnt)
{
    int e = blockIdx.x * blockDim.x + threadIdx.x;
    if (e < EE) atomicAdd(&cnt[clampi(row[e], NN)], 1.f);
}

// out[n] = h2[n,:] . mw1 + mb1
__global__ void k_final(const float* __restrict__ h2, const float* __restrict__ mw1,
                        const float* __restrict__ mb1, float* __restrict__ out)
{
    int wave = (blockIdx.x * 256 + threadIdx.x) >> 6;
    int lane = threadIdx.x & 63;
    if (wave >= NN) return;
    const float4* h4 = (const float4*)(h2 + (size_t)wave * 512);
    const float4* w4 = (const float4*)mw1;
    float s = 0.f;
#pragma unroll
    for (int i = 0; i < 2; ++i) {
        int f = lane * 2 + i;
        float4 a = h4[f], b = w4[f];
        s += a.x * b.x + a.y * b.y + a.z * b.z + a.w * b.w;
    }
    for (int off = 32; off; off >>= 1) s += __shfl_down(s, off);
    if (lane == 0) out[wave] = s + mb1[0];
}

// ------------------------------- host --------------------------------------

#define GRID1(n) dim3(((n) + 255) / 256)

static inline void gemmB0(hipStream_t s, const _Float16* A, const _Float16* Wt, int KT,
                          const float* bias, int ldbias, const int* gbid,
                          void* C, int KTo, int ktOff,
                          int M, int MT, int NT, int relu)
{
    hipLaunchKernelGGL(gemm_blk<0>, dim3(NT, MT), dim3(256), 0, s,
                       A, Wt, KT, bias, ldbias, gbid, C, KTo, ktOff, 0,
                       nullptr, nullptr, M, relu);
}
static inline void gemmB1(hipStream_t s, const _Float16* A, const _Float16* Wt, int KT,
                          const float* bias, int ldbias, const int* gbid,
                          void* C, int ldc, int M, int MT, int NT, int relu)
{
    hipLaunchKernelGGL(gemm_blk<1>, dim3(NT, MT), dim3(256), 0, s,
                       A, Wt, KT, bias, ldbias, gbid, C, 0, 0, ldc,
                       nullptr, nullptr, M, relu);
}
static inline void gemmB2(hipStream_t s, const _Float16* A, const _Float16* Wt, int KT,
                          const float* bias, const int* srow, float* agg,
                          int M, int MT, int NT, int relu)
{
    hipLaunchKernelGGL(gemm_blk<2>, dim3(NT, MT), dim3(256), 0, s,
                       A, Wt, KT, bias, 0, nullptr, nullptr, 0, 0, 0,
                       srow, agg, M, relu);
}

extern "C" void kernel_launch(void* const* d_in, const int* in_sizes, int n_in,
                              void* d_out, int out_size, void* d_ws, size_t ws_size,
                              hipStream_t stream)
{
    const float* x     = (const float*)d_in[0];
    const int*   ei    = (const int*)d_in[1];
    const float* ea    = (const float*)d_in[2];
    const float* u     = (const float*)d_in[3];
    const int*   batch = (const int*)d_in[4];
    const float* w_sel = (const float*)d_in[5];
    const float* b_sel = (const float*)d_in[6];
    const float* ew0 = (const float*)d_in[7];   const float* eb0 = (const float*)d_in[8];
    const float* ew1 = (const float*)d_in[9];   const float* eb1 = (const float*)d_in[10];
    const float* ew2 = (const float*)d_in[11];  const float* eb2 = (const float*)d_in[12];
    const float* ew3 = (const float*)d_in[13];  const float* eb3 = (const float*)d_in[14];
    const float* ew4 = (const float*)d_in[15];  const float* eb4 = (const float*)d_in[16];
    const float* nw0 = (const float*)d_in[17];  const float* nb0 = (const float*)d_in[18];
    const float* nw1 = (const float*)d_in[19];  const float* nb1 = (const float*)d_in[20];
    const float* mw0 = (const float*)d_in[21];  const float* mb0 = (const float*)d_in[22];
    const float* mw1 = (const float*)d_in[23];  const float* mb1 = (const float*)d_in[24];

    const int* row = ei;
    const int* col = ei + EE;

    char* W = (char*)d_ws;
    size_t off = 0;
    auto alloc = [&](size_t bytes) -> char* {
        char* p = W + off;
        off = (off + bytes + 255) & ~(size_t)255;
        return p;
    };
    float*    cnt  = (float*)alloc(20000 * 4);
    float*    agg  = (float*)alloc((size_t)NN * 512 * 4);
    const size_t zeroBytes = off;
    float*    u_r  = (float*)alloc(16 * 256 * 4);
    float*    ub0  = (float*)alloc(16 * 1024 * 4);
    float*    ubm  = (float*)alloc(16 * 512 * 4);
    int*      gbe  = (int*)alloc((size_t)EE * 4);
    _Float16* wh0  = (_Float16*)alloc((size_t)8 * 1 * 4096 * 2);
    _Float16* wh1  = (_Float16*)alloc((size_t)8 * 32 * 4096 * 2);
    _Float16* wh2  = (_Float16*)alloc((size_t)8 * 32 * 4096 * 2);
    _Float16* wh3  = (_Float16*)alloc((size_t)8 * 32 * 4096 * 2);
    _Float16* wh4  = (_Float16*)alloc((size_t)4 * 32 * 4096 * 2);
    _Float16* whn0 = (_Float16*)alloc((size_t)4 * 17 * 4096 * 2);
    _Float16* whn1 = (_Float16*)alloc((size_t)4 * 16 * 4096 * 2);
    _Float16* whm0 = (_Float16*)alloc((size_t)4 * 17 * 4096 * 2);
    const int MTm = (NN + 127) / 128;           // 157
    float*    h2   = (float*)alloc((size_t)NN * 512 * 4);
    _Float16* m_in = (_Float16*)alloc((size_t)MTm * 17 * 4096 * 2);
    const size_t fixedBytes = off;

    // choose edge chunk (depends only on ws_size -> capture-safe).
    static const int ecOpts[] = {25000, 12500, 10000, 5000};
    int EC = 5000;
    for (int i = 0; i < 4; ++i) {
        int ec = ecOpts[i];
        size_t MTRc = (size_t)((ec + 127) / 128) * 128;
        size_t need = fixedBytes + MTRc * 32 * 2 + 2 * (MTRc * 1024 * 2)
                    + MTRc * 544 * 2 + 4096;
        if (need <= ws_size) { EC = ec; break; }
    }
    const int MT  = (EC + 127) / 128;
    const size_t MTR = (size_t)MT * 128;
    _Float16* e_in = (_Float16*)alloc(MTR * 32 * 2);    // [MT][1]
    _Float16* ping = (_Float16*)alloc(MTR * 1024 * 2);  // [MT][32]
    _Float16* pong = (_Float16*)alloc(MTR * 1024 * 2);  // [MT][32]
    _Float16* ninb = (_Float16*)alloc(MTR * 544 * 2);   // [MT][17]
    const int NCH = (EE + EC - 1) / EC;

    (void)hipMemsetAsync(W, 0, zeroBytes, stream);

    hipLaunchKernelGGL(k_u_r, dim3(1024), dim3(256), 0, stream, u, w_sel, b_sel, u_r);
    hipLaunchKernelGGL(k_graph_bias, GRID1(16 * 1024 * 64), dim3(256), 0, stream,
                       u_r, ew0, eb0, ub0, 1024, 275, 19);
    hipLaunchKernelGGL(k_graph_bias, GRID1(16 * 512 * 64), dim3(256), 0, stream,
                       u_r, mw0, mb0, ubm, 512, 777, 521);
    hipLaunchKernelGGL(k_gbe, GRID1(EE), dim3(256), 0, stream, row, batch, gbe);

    auto pack = [&](const float* w, _Float16* wh, int N, int Ksrc, int Kd, int mode) {
        hipLaunchKernelGGL(k_w2h_blk, GRID1(N * Kd), dim3(256), 0, stream, w, wh, N, Ksrc, Kd, mode);
    };
    pack(ew0, wh0, 1024, 275, 32, 1);
    pack(ew1, wh1, 1024, 1024, 1024, 0);
    pack(ew2, wh2, 1024, 1024, 1024, 0);
    pack(ew3, wh3, 1024, 1024, 1024, 0);
    pack(ew4, wh4, 512, 1024, 1024, 0);
    pack(nw0, whn0, 512, 521, 544, 2);
    pack(nw1, whn1, 512, 512, 512, 0);
    pack(mw0, whm0, 512, 777, 544, 2);

    hipLaunchKernelGGL(k_count, GRID1(EE), dim3(256), 0, stream, row, cnt);

    for (int ch = 0; ch < NCH; ++ch) {
        int e0 = ch * EC;
        int ec = EC; if (e0 + ec > EE) ec = EE - e0;
        hipLaunchKernelGGL(k_gather_edge_blk, GRID1((int)MTR * 4), dim3(256), 0, stream,
                           x, ea, row, col, e_in, e0, ec, (int)MTR);
        // l0: K=32, per-graph bias ub0
        gemmB0(stream, e_in, wh0, 1, ub0, 1024, gbe + e0, ping, 32, 0, ec, MT, 8, 1);
        gemmB0(stream, ping, wh1, 32, eb1, 0, nullptr, pong, 32, 0, ec, MT, 8, 1);
        gemmB0(stream, pong, wh2, 32, eb2, 0, nullptr, ping, 32, 0, ec, MT, 8, 1);
        gemmB0(stream, ping, wh3, 32, eb3, 0, nullptr, pong, 32, 0, ec, MT, 8, 1);
        // ew4 -> ninb (blocked, kt offset 1), no relu on edge_out
        gemmB0(stream, pong, wh4, 32, eb4, 0, nullptr, ninb, 17, 1, ec, MT, 4, 0);
        hipLaunchKernelGGL(k_gather_nin0, GRID1((int)MTR * 4), dim3(256), 0, stream,
                           x, col, ninb, e0, ec, (int)MTR);
        gemmB0(stream, ninb, whn0, 17, nb0, 0, nullptr, ping, 16, 0, ec, MT, 4, 1);
        // n1: fused COALESCED scatter-add into agg (mode 2)
        gemmB2(stream, ping, whn1, 16, nb1, row + e0, agg, ec, MT, 4, 1);
    }

    hipLaunchKernelGGL(k_gather_min, GRID1((int)(MTm * 128) * 68), dim3(256), 0, stream,
                       x, agg, cnt, m_in, MTm * 128);
    // m0: f32 row-major out, per-graph bias ubm (gbid = batch)
    gemmB1(stream, m_in, whm0, 17, ubm, 512, batch, h2, 512, NN, MTm, 4, 1);
    hipLaunchKernelGGL(k_final, dim3((NN + 3) / 4), dim3(256), 0, stream,
                       h2, mw1, mb1, (float*)d_out);
}

// Round 12
// 1525.731 us; speedup vs baseline: 1.7179x; 1.0119x over previous
//
#include <hip/hip_runtime.h>

// ---------------------------------------------------------------------------
// OGRENet GraphNet block — f16 MFMA, BLOCKED operands, BK=64, lb(256,4).
// Blocked layout (f16): offset(m,k) = ((mt*KTo + kt)*4 + kg)*1024 + r*8 + ko
// R12: ew4+nw0 FOLDED (no relu between them in the reference):
//   W_comb = nw0[:,9:521] @ ew4  (on-device blocked GEMM, f32 acc)
//   nc GEMM: [h3 | x[col]] (K=1056) @ [W_comb | nw0[:,:9]]^T + bfused
// eliminates edge_out materialization entirely.
//  mode 0: re-block C via 2-pass LDS transpose; mode 1: f32 row-major;
//  mode 2: fused scatter-add -> COALESCED atomics.
// [R8: template MODE; R10: BK=64 needs lb(256,4); R7: rocprof replay
//  overstates atomic kernels ~20x — trust timed totals.]
// ---------------------------------------------------------------------------

#define NN 20000
#define EE 100000
#define BB 16

typedef _Float16 f16x8 __attribute__((ext_vector_type(8)));
typedef _Float16 f16x4 __attribute__((ext_vector_type(4)));
typedef float f32x4 __attribute__((ext_vector_type(4)));

__device__ __forceinline__ int clampi(int v, int hi) {
    return v < 0 ? 0 : (v >= hi ? hi - 1 : v);
}

__device__ __forceinline__ void gld_lds16(const void* g, void* l) {
    __builtin_amdgcn_global_load_lds(
        (const __attribute__((address_space(1))) unsigned int*)g,
        (__attribute__((address_space(3))) unsigned int*)l, 16, 0, 0);
}

// ------------------------- blocked f16 MFMA GEMM ---------------------------
template <int MODE>
__global__ __launch_bounds__(256, 4) void gemm_blk(
    const _Float16* __restrict__ A,      // blocked [MT][KTs]
    const _Float16* __restrict__ Wt,     // blocked [NT][KT] (dense)
    int KT, int KTs,
    const float* __restrict__ bias, int ldbias, const int* __restrict__ gbid,
    void* __restrict__ C, int KTo, int ktOff,   // mode 0: blocked f16 out
    int ldc,                                    // mode 1: f32 row-major out
    const int* __restrict__ srow, float* __restrict__ agg,  // mode 2
    int M, int relu)
{
    __shared__ char smem[32768];   // staging 2x16KB | m0 tr 16.9KB | m2 trf 16.6KB
    _Float16* As = (_Float16*)smem;          // 8192 f16
    _Float16* Bs = As + 8192;

    const int tid  = threadIdx.x;
    const int lane = tid & 63;
    const int wid  = tid >> 6;
    const int wm = (wid & 1) << 6;
    const int wn = (wid >> 1) << 6;

    // XCD swizzle: panel p's column-blocks share f%8 (same XCD)
    const int nb = gridDim.x;
    const int MT = gridDim.y;
    int f = blockIdx.y * nb + blockIdx.x;
    const int MT8 = MT & ~7;
    int p, c;
    if (f < MT8 * nb) {
        c = (f >> 3) % nb;
        p = (f & 7) + 8 * ((f >> 3) / nb);
    } else {
        int g = f - MT8 * nb;
        p = MT8 + g / nb;
        c = g % nb;
    }

    f32x4 acc[4][4];
#pragma unroll
    for (int i = 0; i < 4; ++i)
#pragma unroll
        for (int j = 0; j < 4; ++j) acc[i][j] = (f32x4){0.f, 0.f, 0.f, 0.f};

    const _Float16* pA = A + (size_t)p * KTs * 4096;
    const _Float16* pB = Wt + (size_t)c * KT * 4096;
    const int cb0 = wid * 64;
    const int cb1 = 256 + wid * 64;
    const int kq  = (lane >> 4) * 128;
    const int l15 = lane & 15;
    const int l4  = (lane >> 4) << 2;

    // main loop: BK=64 (two kt blocks per barrier pair)
    int kt = 0;
    for (; kt + 2 <= KT; kt += 2) {
        __syncthreads();
        gld_lds16(pA + (size_t)(cb0 + lane) * 8,        As + cb0 * 8);
        gld_lds16(pA + (size_t)(cb1 + lane) * 8,        As + cb1 * 8);
        gld_lds16(pA + 4096 + (size_t)(cb0 + lane) * 8, As + 4096 + cb0 * 8);
        gld_lds16(pA + 4096 + (size_t)(cb1 + lane) * 8, As + 4096 + cb1 * 8);
        gld_lds16(pB + (size_t)(cb0 + lane) * 8,        Bs + cb0 * 8);
        gld_lds16(pB + (size_t)(cb1 + lane) * 8,        Bs + cb1 * 8);
        gld_lds16(pB + 4096 + (size_t)(cb0 + lane) * 8, Bs + 4096 + cb0 * 8);
        gld_lds16(pB + 4096 + (size_t)(cb1 + lane) * 8, Bs + 4096 + cb1 * 8);
        pA += 8192; pB += 8192;
        __syncthreads();

#pragma unroll
        for (int s = 0; s < 2; ++s) {
            f16x8 af[4], bf[4];
            const int sb = s * 4096;
#pragma unroll
            for (int i = 0; i < 4; ++i)
                af[i] = *(const f16x8*)(As + sb + (size_t)((kq + wm + i * 16 + l15) << 3));
#pragma unroll
            for (int j = 0; j < 4; ++j)
                bf[j] = *(const f16x8*)(Bs + sb + (size_t)((kq + wn + j * 16 + l15) << 3));
#pragma unroll
            for (int i = 0; i < 4; ++i)
#pragma unroll
                for (int j = 0; j < 4; ++j)
                    acc[i][j] = __builtin_amdgcn_mfma_f32_16x16x32_f16(af[i], bf[j], acc[i][j], 0, 0, 0);
        }
    }
    // leftover: BK=32
    if (kt < KT) {
        __syncthreads();
        gld_lds16(pA + (size_t)(cb0 + lane) * 8, As + cb0 * 8);
        gld_lds16(pA + (size_t)(cb1 + lane) * 8, As + cb1 * 8);
        gld_lds16(pB + (size_t)(cb0 + lane) * 8, Bs + cb0 * 8);
        gld_lds16(pB + (size_t)(cb1 + lane) * 8, Bs + cb1 * 8);
        __syncthreads();
        f16x8 af[4], bf[4];
#pragma unroll
        for (int i = 0; i < 4; ++i)
            af[i] = *(const f16x8*)(As + (size_t)((kq + wm + i * 16 + l15) << 3));
#pragma unroll
        for (int j = 0; j < 4; ++j)
            bf[j] = *(const f16x8*)(Bs + (size_t)((kq + wn + j * 16 + l15) << 3));
#pragma unroll
        for (int i = 0; i < 4; ++i)
#pragma unroll
            for (int j = 0; j < 4; ++j)
                acc[i][j] = __builtin_amdgcn_mfma_f32_16x16x32_f16(af[i], bf[j], acc[i][j], 0, 0, 0);
    }

    if (MODE == 0) {
        // re-block C through LDS, two passes of 64 rows (tr = [64][132] f16)
        _Float16* tr = (_Float16*)smem;
#pragma unroll
        for (int pass = 0; pass < 2; ++pass) {
            __syncthreads();
            if (wm == pass * 64) {
#pragma unroll
                for (int i = 0; i < 4; ++i) {
#pragma unroll
                    for (int v = 0; v < 4; ++v) {
                        const int lr = i * 16 + l4 + v;
                        const float* brow = bias;
                        if (gbid) {
                            int m = p * 128 + pass * 64 + lr;
                            if (m >= M) m = M - 1;
                            brow = bias + (size_t)clampi(gbid[m], BB) * ldbias;
                        }
#pragma unroll
                        for (int j = 0; j < 4; ++j) {
                            const int cc = wn + j * 16 + l15;
                            float val = acc[i][j][v] + brow[c * 128 + cc];
                            if (relu) val = fmaxf(val, 0.f);
                            tr[lr * 132 + cc] = (_Float16)val;
                        }
                    }
                }
            }
            __syncthreads();
#pragma unroll
            for (int it = 0; it < 4; ++it) {
                const int id = it * 256 + tid;
                const int r  = id & 63;
                const int cg = id >> 6;
                f16x4 lo = *(const f16x4*)(tr + r * 132 + cg * 8);
                f16x4 hi = *(const f16x4*)(tr + r * 132 + cg * 8 + 4);
                f16x8 v8;
#pragma unroll
                for (int t = 0; t < 4; ++t) { v8[t] = lo[t]; v8[t + 4] = hi[t]; }
                const int kti = ktOff + (c << 2) + (cg >> 2);
                const int gr  = pass * 64 + r;
                size_t o = (((size_t)p * KTo + kti) * 4 + (cg & 3)) * 1024 + (size_t)gr * 8;
                *(f16x8*)((_Float16*)C + o) = v8;
            }
        }
    } else if (MODE == 1) {
#pragma unroll
        for (int i = 0; i < 4; ++i) {
#pragma unroll
            for (int v = 0; v < 4; ++v) {
                const int m = p * 128 + wm + i * 16 + l4 + v;
                if (m >= M) continue;
                const float* brow = bias;
                if (gbid) brow = bias + (size_t)clampi(gbid[m], BB) * ldbias;
#pragma unroll
                for (int j = 0; j < 4; ++j) {
                    const int col = c * 128 + wn + j * 16 + l15;
                    float val = acc[i][j][v] + brow[col];
                    if (relu) val = fmaxf(val, 0.f);
                    ((float*)C)[(size_t)m * ldc + col] = val;
                }
            }
        }
    } else {
        // mode 2: fused coalesced scatter-add. 4 passes of 32 rows.
        float* trf = (float*)smem;   // [32][130] f32, 16640 B
#pragma unroll
        for (int pass = 0; pass < 4; ++pass) {
            __syncthreads();
            if (wm == ((pass >> 1) << 6)) {
                const int i0 = (pass & 1) << 1;
#pragma unroll
                for (int ii = 0; ii < 2; ++ii) {
                    const int i = i0 + ii;
                    const int lr = ii * 16 + l4;
#pragma unroll
                    for (int v = 0; v < 4; ++v) {
#pragma unroll
                        for (int j = 0; j < 4; ++j) {
                            const int cc = wn + j * 16 + l15;
                            float val = acc[i][j][v] + bias[c * 128 + cc];
                            if (relu) val = fmaxf(val, 0.f);
                            trf[(lr + v) * 130 + cc] = val;
                        }
                    }
                }
            }
            __syncthreads();
            const int ebase = p * 128 + pass * 32;
#pragma unroll
            for (int it = 0; it < 16; ++it) {
                const int id = it * 256 + tid;
                const int lr = id >> 7;
                const int colg = id & 127;
                const int el = ebase + lr;
                if (el < M) {
                    const int node = clampi(srow[el], NN);
                    atomicAdd(&agg[(size_t)node * 512 + c * 128 + colg],
                              trf[lr * 130 + colg]);
                }
            }
        }
    }
}

// ------------------------- helper kernels ----------------------------------

// fp32 -> blocked f16 [N/128][Kd/32].
// mode 0: plain src[n][k], k<Ksrc
// mode 1: e0 (k<19)
// mode 2: pack544 (k<9 | 32<=k<544 -> src col 9+(k-32))
// mode 4: transpose: v = (k<Ksrc) ? src[k*N + n] : 0
// mode 5: tail512: v = src[n][9+k], k<512 (Ksrc = full row len)
__global__ void k_w2h_blk(const float* __restrict__ src, _Float16* __restrict__ dst,
                          int N, int Ksrc, int Kd, int mode)
{
    int t = blockIdx.x * blockDim.x + threadIdx.x;
    if (t >= N * Kd) return;
    int n = t / Kd, k = t - n * Kd;
    float v = 0.f;
    if (mode == 0)      { if (k < Ksrc) v = src[(size_t)n * Ksrc + k]; }
    else if (mode == 1) { if (k < 19) v = src[(size_t)n * 275 + k]; }
    else if (mode == 2) { if (k < 9) v = src[(size_t)n * Ksrc + k];
                          else if (k >= 32 && k < 544) v = src[(size_t)n * Ksrc + 9 + (k - 32)]; }
    else if (mode == 4) { if (k < Ksrc) v = src[(size_t)k * N + n]; }
    else                { v = src[(size_t)n * Ksrc + 9 + k]; }
    int KT = Kd >> 5;
    int nt = n >> 7, r = n & 127, kt = k >> 5, kg = (k >> 3) & 3, ko = k & 7;
    dst[(((size_t)nt * KT + kt) * 4 + kg) * 1024 + (size_t)r * 8 + ko] = (_Float16)v;
}

// whnc kt32 slot: k' 0..31, value = nw0[n][k'] for k'<9 else 0
__global__ void k_fill_w32(const float* __restrict__ nw0, _Float16* __restrict__ whnc)
{
    int t = blockIdx.x * blockDim.x + threadIdx.x;
    if (t >= 512 * 32) return;
    int n = t >> 5, k = t & 31;
    float v = (k < 9) ? nw0[(size_t)n * 521 + k] : 0.f;
    int nt = n >> 7, r = n & 127, kg = (k >> 3) & 3, ko = k & 7;
    whnc[(((size_t)nt * 33 + 32) * 4 + kg) * 1024 + (size_t)r * 8 + ko] = (_Float16)v;
}

// bfused[n] = dot(nw0[n][9:521], eb4) + nb0[n]; one wave per n
__global__ void k_bfuse(const float* __restrict__ nw0, const float* __restrict__ eb4,
                        const float* __restrict__ nb0, float* __restrict__ bf)
{
    int wave = (blockIdx.x * 256 + threadIdx.x) >> 6;
    int lane = threadIdx.x & 63;
    if (wave >= 512) return;
    const float* wr = nw0 + (size_t)wave * 521 + 9;
    float s = 0.f;
#pragma unroll
    for (int i = 0; i < 8; ++i) s += wr[lane * 8 + i] * eb4[lane * 8 + i];
    for (int off = 32; off; off >>= 1) s += __shfl_down(s, off);
    if (lane == 0) bf[wave] = s + nb0[wave];
}

// u_r[16,256] fp32
__global__ void k_u_r(const float* __restrict__ u, const float* __restrict__ w_sel,
                      const float* __restrict__ b_sel, float* __restrict__ u_r)
{
    int wave = (blockIdx.x * 256 + threadIdx.x) >> 6;
    int lane = threadIdx.x & 63;
    int b = wave >> 8, n = wave & 255;
    const float4* u4 = (const float4*)(u + (size_t)b * 4096);
    const float4* w4 = (const float4*)(w_sel + (size_t)n * 4096);
    float s = 0.f;
    for (int i = lane; i < 1024; i += 64) {
        float4 a = u4[i], c = w4[i];
        s += a.x * c.x + a.y * c.y + a.z * c.z + a.w * c.w;
    }
    for (int off = 32; off; off >>= 1) s += __shfl_down(s, off);
    if (lane == 0) u_r[b * 256 + n] = s + b_sel[n];
}

// ub[16][Nout] = u_r @ w[:, koff:koff+256]^T + b
__global__ void k_graph_bias(const float* __restrict__ u_r, const float* __restrict__ w,
                             const float* __restrict__ b, float* __restrict__ ub,
                             int Nout, int Ksrc, int koff)
{
    int wave = (blockIdx.x * 256 + threadIdx.x) >> 6;
    int lane = threadIdx.x & 63;
    if (wave >= 16 * Nout) return;
    int g = wave / Nout, n = wave - g * Nout;
    const float* ur = u_r + (size_t)g * 256;
    const float* wr = w + (size_t)n * Ksrc + koff;
    float s = 0.f;
#pragma unroll
    for (int i = 0; i < 4; ++i) s += ur[lane * 4 + i] * wr[lane * 4 + i];
    for (int off = 32; off; off >>= 1) s += __shfl_down(s, off);
    if (lane == 0) ub[(size_t)g * Nout + n] = s + b[n];
}

// gbe + per-node edge count in one pass
__global__ void k_gbe(const int* __restrict__ row, const int* __restrict__ batch,
                      int* __restrict__ gbe, float* __restrict__ cnt)
{
    int e = blockIdx.x * blockDim.x + threadIdx.x;
    if (e >= EE) return;
    int r = clampi(row[e], NN);
    gbe[e] = clampi(batch[r], BB);
    atomicAdd(&cnt[r], 1.f);
}

// e_in blocked [MT][1]: cols = [x[row](9) | x[col](9) | ea | 0..]
__global__ void k_gather_edge_blk(const float* __restrict__ x, const float* __restrict__ ea,
                                  const int* __restrict__ row, const int* __restrict__ col,
                                  _Float16* __restrict__ dst, int e0, int ec, int MTR)
{
    int t = blockIdx.x * blockDim.x + threadIdx.x;
    if (t >= MTR * 4) return;
    int r = t >> 2, kg = t & 3;
    int e = e0 + r; int emax = e0 + ec - 1;
    if (e > emax) e = emax;
    int ri = clampi(row[e], NN), ci = clampi(col[e], NN);
    f16x8 v;
#pragma unroll
    for (int j = 0; j < 8; ++j) {
        int cc = kg * 8 + j;
        float fv = 0.f;
        if (cc < 9)       fv = x[(size_t)ri * 9 + cc];
        else if (cc < 18) fv = x[(size_t)ci * 9 + (cc - 9)];
        else if (cc == 18) fv = ea[e];
        v[j] = (_Float16)fv;
    }
    *(f16x8*)(dst + (size_t)(r >> 7) * 4096 + (size_t)kg * 1024 + (size_t)(r & 127) * 8) = v;
}

// x[col] into kt=32 slot of pong [MT][33]
__global__ void k_gather_xc(const float* __restrict__ x, const int* __restrict__ col,
                            _Float16* __restrict__ dst, int e0, int ec, int MTR)
{
    int t = blockIdx.x * blockDim.x + threadIdx.x;
    if (t >= MTR * 4) return;
    int r = t >> 2, kg = t & 3;
    int e = e0 + r; int emax = e0 + ec - 1;
    if (e > emax) e = emax;
    int ci = clampi(col[e], NN);
    f16x8 v = (f16x8)(_Float16)0.f;
#pragma unroll
    for (int j = 0; j < 8; ++j) {
        int cc = kg * 8 + j;
        if (cc < 9) v[j] = (_Float16)x[(size_t)ci * 9 + cc];
    }
    *(f16x8*)(dst + (((size_t)(r >> 7) * 33 + 32) * 4 + kg) * 1024 + (size_t)(r & 127) * 8) = v;
}

// m_in blocked [MTm][17]: cols = [x(9)|pad23 | agg/cnt(512)]
__global__ void k_gather_min(const float* __restrict__ x, const float* __restrict__ agg,
                             const float* __restrict__ cnt, _Float16* __restrict__ dst, int MTR)
{
    int t = blockIdx.x * blockDim.x + threadIdx.x;
    if (t >= MTR * 68) return;
    int r = t / 68, q = t - r * 68;
    int kt = q >> 2, kg = q & 3;
    int n = r < NN ? r : NN - 1;
    f16x8 v = (f16x8)(_Float16)0.f;
    if (kt == 0) {
#pragma unroll
        for (int j = 0; j < 8; ++j) {
            int cc = kg * 8 + j;
            if (cc < 9) v[j] = (_Float16)x[(size_t)n * 9 + cc];
        }
    } else {
        float inv = 1.f / fmaxf(cnt[n], 1.f);
        int cbase = (kt - 1) * 32 + kg * 8;
        const float4* ap = (const float4*)(agg + (size_t)n * 512 + cbase);
        float4 a0 = ap[0], a1 = ap[1];
        v[0] = (_Float16)(a0.x * inv); v[1] = (_Float16)(a0.y * inv);
        v[2] = (_Float16)(a0.z * inv); v[3] = (_Float16)(a0.w * inv);
        v[4] = (_Float16)(a1.x * inv); v[5] = (_Float16)(a1.y * inv);
        v[6] = (_Float16)(a1.z * inv); v[7] = (_Float16)(a1.w * inv);
    }
    *(f16x8*)(dst + ((size_t)(r >> 7) * 17 + kt) * 4096 + (size_t)kg * 1024 + (size_t)(r & 127) * 8) = v;
}

// out[n] = h2[n,:] . mw1 + mb1
__global__ void k_final(const float* __restrict__ h2, const float* __restrict__ mw1,
                        const float* __restrict__ mb1, float* __restrict__ out)
{
    int wave = (blockIdx.x * 256 + threadIdx.x) >> 6;
    int lane = threadIdx.x & 63;
    if (wave >= NN) return;
    const float4* h4 = (const float4*)(h2 + (size_t)wave * 512);
    const float4* w4 = (const float4*)mw1;
    float s = 0.f;
#pragma unroll
    for (int i = 0; i < 2; ++i) {
        int f = lane * 2 + i;
        float4 a = h4[f], b = w4[f];
        s += a.x * b.x + a.y * b.y + a.z * b.z + a.w * b.w;
    }
    for (int off = 32; off; off >>= 1) s += __shfl_down(s, off);
    if (lane == 0) out[wave] = s + mb1[0];
}

// ------------------------------- host --------------------------------------

#define GRID1(n) dim3(((n) + 255) / 256)

static inline void gemmB0(hipStream_t s, const _Float16* A, const _Float16* Wt, int KT, int KTs,
                          const float* bias, int ldbias, const int* gbid,
                          void* C, int KTo, int ktOff,
                          int M, int MT, int NT, int relu)
{
    hipLaunchKernelGGL(gemm_blk<0>, dim3(NT, MT), dim3(256), 0, s,
                       A, Wt, KT, KTs, bias, ldbias, gbid, C, KTo, ktOff, 0,
                       nullptr, nullptr, M, relu);
}
static inline void gemmB1(hipStream_t s, const _Float16* A, const _Float16* Wt, int KT, int KTs,
                          const float* bias, int ldbias, const int* gbid,
                          void* C, int ldc, int M, int MT, int NT, int relu)
{
    hipLaunchKernelGGL(gemm_blk<1>, dim3(NT, MT), dim3(256), 0, s,
                       A, Wt, KT, KTs, bias, ldbias, gbid, C, 0, 0, ldc,
                       nullptr, nullptr, M, relu);
}
static inline void gemmB2(hipStream_t s, const _Float16* A, const _Float16* Wt, int KT, int KTs,
                          const float* bias, const int* srow, float* agg,
                          int M, int MT, int NT, int relu)
{
    hipLaunchKernelGGL(gemm_blk<2>, dim3(NT, MT), dim3(256), 0, s,
                       A, Wt, KT, KTs, bias, 0, nullptr, nullptr, 0, 0, 0,
                       srow, agg, M, relu);
}

extern "C" void kernel_launch(void* const* d_in, const int* in_sizes, int n_in,
                              void* d_out, int out_size, void* d_ws, size_t ws_size,
                              hipStream_t stream)
{
    const float* x     = (const float*)d_in[0];
    const int*   ei    = (const int*)d_in[1];
    const float* ea    = (const float*)d_in[2];
    const float* u     = (const float*)d_in[3];
    const int*   batch = (const int*)d_in[4];
    const float* w_sel = (const float*)d_in[5];
    const float* b_sel = (const float*)d_in[6];
    const float* ew0 = (const float*)d_in[7];   const float* eb0 = (const float*)d_in[8];
    const float* ew1 = (const float*)d_in[9];   const float* eb1 = (const float*)d_in[10];
    const float* ew2 = (const float*)d_in[11];  const float* eb2 = (const float*)d_in[12];
    const float* ew3 = (const float*)d_in[13];  const float* eb3 = (const float*)d_in[14];
    const float* ew4 = (const float*)d_in[15];  const float* eb4 = (const float*)d_in[16];
    const float* nw0 = (const float*)d_in[17];  const float* nb0 = (const float*)d_in[18];
    const float* nw1 = (const float*)d_in[19];  const float* nb1 = (const float*)d_in[20];
    const float* mw0 = (const float*)d_in[21];  const float* mb0 = (const float*)d_in[22];
    const float* mw1 = (const float*)d_in[23];  const float* mb1 = (const float*)d_in[24];

    const int* row = ei;
    const int* col = ei + EE;

    char* W = (char*)d_ws;
    size_t off = 0;
    auto alloc = [&](size_t bytes) -> char* {
        char* p = W + off;
        off = (off + bytes + 255) & ~(size_t)255;
        return p;
    };
    float*    cnt   = (float*)alloc(20000 * 4);
    float*    agg   = (float*)alloc((size_t)NN * 512 * 4);
    float*    zbias = (float*)alloc(1024 * 4);          // stays zero (for W_comb GEMM)
    const size_t zeroBytes = off;
    float*    u_r  = (float*)alloc(16 * 256 * 4);
    float*    ub0  = (float*)alloc(16 * 1024 * 4);
    float*    ubm  = (float*)alloc(16 * 512 * 4);
    float*    bfu  = (float*)alloc(512 * 4);            // fused nc bias
    int*      gbe  = (int*)alloc((size_t)EE * 4);
    _Float16* wh0   = (_Float16*)alloc((size_t)8 * 1 * 4096 * 2);
    _Float16* wh1   = (_Float16*)alloc((size_t)8 * 32 * 4096 * 2);
    _Float16* wh2   = (_Float16*)alloc((size_t)8 * 32 * 4096 * 2);
    _Float16* wh3   = (_Float16*)alloc((size_t)8 * 32 * 4096 * 2);
    _Float16* whnc  = (_Float16*)alloc((size_t)4 * 33 * 4096 * 2);  // [W_comb | nw0_x]
    _Float16* whn1  = (_Float16*)alloc((size_t)4 * 16 * 4096 * 2);
    _Float16* whm0  = (_Float16*)alloc((size_t)4 * 17 * 4096 * 2);
    _Float16* nw0eoB= (_Float16*)alloc((size_t)4 * 16 * 4096 * 2);  // nw0[:,9:521] blocked
    _Float16* ew4T  = (_Float16*)alloc((size_t)8 * 16 * 4096 * 2);  // ew4^T blocked
    const int MTm = (NN + 127) / 128;           // 157
    float*    h2   = (float*)alloc((size_t)NN * 512 * 4);
    _Float16* m_in = (_Float16*)alloc((size_t)MTm * 17 * 4096 * 2);
    const size_t fixedBytes = off;

    // choose edge chunk (depends only on ws_size -> capture-safe).
    static const int ecOpts[] = {25000, 12500, 10000, 5000};
    int EC = 5000;
    for (int i = 0; i < 4; ++i) {
        int ec = ecOpts[i];
        size_t MTRc = (size_t)((ec + 127) / 128) * 128;
        size_t need = fixedBytes + MTRc * 64 + 2 * (MTRc * 2112) + 4096;
        if (need <= ws_size) { EC = ec; break; }
    }
    const int MT  = (EC + 127) / 128;
    const size_t MTR = (size_t)MT * 128;
    _Float16* e_in = (_Float16*)alloc(MTR * 64);        // [MT][1]
    _Float16* ping = (_Float16*)alloc(MTR * 2112);      // [MT][33]
    _Float16* pong = (_Float16*)alloc(MTR * 2112);      // [MT][33]
    const int NCH = (EE + EC - 1) / EC;

    (void)hipMemsetAsync(W, 0, zeroBytes, stream);

    hipLaunchKernelGGL(k_u_r, dim3(1024), dim3(256), 0, stream, u, w_sel, b_sel, u_r);
    hipLaunchKernelGGL(k_graph_bias, GRID1(16 * 1024 * 64), dim3(256), 0, stream,
                       u_r, ew0, eb0, ub0, 1024, 275, 19);
    hipLaunchKernelGGL(k_graph_bias, GRID1(16 * 512 * 64), dim3(256), 0, stream,
                       u_r, mw0, mb0, ubm, 512, 777, 521);
    hipLaunchKernelGGL(k_gbe, GRID1(EE), dim3(256), 0, stream, row, batch, gbe, cnt);
    hipLaunchKernelGGL(k_bfuse, dim3(128), dim3(256), 0, stream, nw0, eb4, nb0, bfu);

    auto pack = [&](const float* w, _Float16* wh, int N, int Ksrc, int Kd, int mode) {
        hipLaunchKernelGGL(k_w2h_blk, GRID1(N * Kd), dim3(256), 0, stream, w, wh, N, Ksrc, Kd, mode);
    };
    pack(ew0, wh0, 1024, 275, 32, 1);
    pack(ew1, wh1, 1024, 1024, 1024, 0);
    pack(ew2, wh2, 1024, 1024, 1024, 0);
    pack(ew3, wh3, 1024, 1024, 1024, 0);
    pack(nw1, whn1, 512, 512, 512, 0);
    pack(mw0, whm0, 512, 777, 544, 2);
    pack(nw0, nw0eoB, 512, 521, 512, 5);    // nw0[:,9:521]
    pack(ew4, ew4T, 1024, 512, 512, 4);     // ew4^T  (v = ew4[k][n])
    // W_comb = nw0eo @ ew4 : M=512, N=1024, K=512 -> whnc kt 0..31 (blocked out)
    gemmB0(stream, nw0eoB, ew4T, 16, 16, zbias, 0, nullptr, whnc, 33, 0, 512, 4, 8, 0);
    hipLaunchKernelGGL(k_fill_w32, GRID1(512 * 32), dim3(256), 0, stream, nw0, whnc);

    for (int ch = 0; ch < NCH; ++ch) {
        int e0 = ch * EC;
        int ec = EC; if (e0 + ec > EE) ec = EE - e0;
        hipLaunchKernelGGL(k_gather_edge_blk, GRID1((int)MTR * 4), dim3(256), 0, stream,
                           x, ea, row, col, e_in, e0, ec, (int)MTR);
        // l0: K=32, per-graph bias ub0
        gemmB0(stream, e_in, wh0, 1, 1, ub0, 1024, gbe + e0, ping, 33, 0, ec, MT, 8, 1);
        gemmB0(stream, ping, wh1, 32, 33, eb1, 0, nullptr, pong, 33, 0, ec, MT, 8, 1);
        gemmB0(stream, pong, wh2, 32, 33, eb2, 0, nullptr, ping, 33, 0, ec, MT, 8, 1);
        gemmB0(stream, ping, wh3, 32, 33, eb3, 0, nullptr, pong, 33, 0, ec, MT, 8, 1);
        // x[col] into pong kt=32
        hipLaunchKernelGGL(k_gather_xc, GRID1((int)MTR * 4), dim3(256), 0, stream,
                           x, col, pong, e0, ec, (int)MTR);
        // nc: fused (ew4+nw0) GEMM, K=1056
        gemmB0(stream, pong, whnc, 33, 33, bfu, 0, nullptr, ping, 16, 0, ec, MT, 4, 1);
        // n1: fused COALESCED scatter-add into agg (mode 2)
        gemmB2(stream, ping, whn1, 16, 16, nb1, row + e0, agg, ec, MT, 4, 1);
    }

    hipLaunchKernelGGL(k_gather_min, GRID1((int)(MTm * 128) * 68), dim3(256), 0, stream,
                       x, agg, cnt, m_in, MTm * 128);
    // m0: f32 row-major out, per-graph bias ubm (gbid = batch)
    gemmB1(stream, m_in, whm0, 17, 17, ubm, 512, batch, h2, 512, NN, MTm, 4, 1);
    hipLaunchKernelGGL(k_final, dim3((NN + 3) / 4), dim3(256), 0, stream,
                       h2, mw1, mb1, (float*)d_out);
}

// Round 13
// 1455.625 us; speedup vs baseline: 1.8007x; 1.0482x over previous
//
#include <hip/hip_runtime.h>

// ---------------------------------------------------------------------------
// OGRENet GraphNet block — f16 MFMA, BLOCKED operands, BK=64, lb(256,4).
// Blocked layout (f16): offset(m,k) = ((mt*KTo + kt)*4 + kg)*1024 + r*8 + ko
// R12: ew4+nw0 folded (W_comb = nw0[:,9:521]@ew4, on-device).
// R13: k_final folded into m0 (MODE=3 dot epilogue); xc-gather merged into
// edge gather. Modes: 0 blocked f16 out; 1 f32 row-major; 2 fused coalesced
// scatter-add; 3 fused final dot (out[m] += relu(acc+bias).mw1, atomic).
// [R8: template MODE; R10/R11: BK=64 + lb(256,4) -> VGPR 60, 4 blk/CU;
//  R7: rocprof replay overstates atomic kernels ~20x — trust timed totals.]
// ---------------------------------------------------------------------------

#define NN 20000
#define EE 100000
#define BB 16

typedef _Float16 f16x8 __attribute__((ext_vector_type(8)));
typedef _Float16 f16x4 __attribute__((ext_vector_type(4)));
typedef float f32x4 __attribute__((ext_vector_type(4)));

__device__ __forceinline__ int clampi(int v, int hi) {
    return v < 0 ? 0 : (v >= hi ? hi - 1 : v);
}

__device__ __forceinline__ void gld_lds16(const void* g, void* l) {
    __builtin_amdgcn_global_load_lds(
        (const __attribute__((address_space(1))) unsigned int*)g,
        (__attribute__((address_space(3))) unsigned int*)l, 16, 0, 0);
}

// ------------------------- blocked f16 MFMA GEMM ---------------------------
template <int MODE>
__global__ __launch_bounds__(256, 4) void gemm_blk(
    const _Float16* __restrict__ A,      // blocked [MT][KTs]
    const _Float16* __restrict__ Wt,     // blocked [NT][KT] (dense)
    int KT, int KTs,
    const float* __restrict__ bias, int ldbias, const int* __restrict__ gbid,
    void* __restrict__ C, int KTo, int ktOff,   // mode 0: blocked f16 out
    int ldc,                                    // mode 1: f32 row-major out
    const int* __restrict__ srow, float* __restrict__ aux,  // m2: agg; m3: mw1
    int M, int relu)
{
    __shared__ char smem[32768];   // staging 2x16KB | m0 tr 16.9KB | m2 trf 16.6KB
    _Float16* As = (_Float16*)smem;          // 8192 f16
    _Float16* Bs = As + 8192;

    const int tid  = threadIdx.x;
    const int lane = tid & 63;
    const int wid  = tid >> 6;
    const int wm = (wid & 1) << 6;
    const int wn = (wid >> 1) << 6;

    // XCD swizzle: panel p's column-blocks share f%8 (same XCD)
    const int nb = gridDim.x;
    const int MT = gridDim.y;
    int f = blockIdx.y * nb + blockIdx.x;
    const int MT8 = MT & ~7;
    int p, c;
    if (f < MT8 * nb) {
        c = (f >> 3) % nb;
        p = (f & 7) + 8 * ((f >> 3) / nb);
    } else {
        int g = f - MT8 * nb;
        p = MT8 + g / nb;
        c = g % nb;
    }

    f32x4 acc[4][4];
#pragma unroll
    for (int i = 0; i < 4; ++i)
#pragma unroll
        for (int j = 0; j < 4; ++j) acc[i][j] = (f32x4){0.f, 0.f, 0.f, 0.f};

    const _Float16* pA = A + (size_t)p * KTs * 4096;
    const _Float16* pB = Wt + (size_t)c * KT * 4096;
    const int cb0 = wid * 64;
    const int cb1 = 256 + wid * 64;
    const int kq  = (lane >> 4) * 128;
    const int l15 = lane & 15;
    const int l4  = (lane >> 4) << 2;

    // main loop: BK=64 (two kt blocks per barrier pair)
    int kt = 0;
    for (; kt + 2 <= KT; kt += 2) {
        __syncthreads();
        gld_lds16(pA + (size_t)(cb0 + lane) * 8,        As + cb0 * 8);
        gld_lds16(pA + (size_t)(cb1 + lane) * 8,        As + cb1 * 8);
        gld_lds16(pA + 4096 + (size_t)(cb0 + lane) * 8, As + 4096 + cb0 * 8);
        gld_lds16(pA + 4096 + (size_t)(cb1 + lane) * 8, As + 4096 + cb1 * 8);
        gld_lds16(pB + (size_t)(cb0 + lane) * 8,        Bs + cb0 * 8);
        gld_lds16(pB + (size_t)(cb1 + lane) * 8,        Bs + cb1 * 8);
        gld_lds16(pB + 4096 + (size_t)(cb0 + lane) * 8, Bs + 4096 + cb0 * 8);
        gld_lds16(pB + 4096 + (size_t)(cb1 + lane) * 8, Bs + 4096 + cb1 * 8);
        pA += 8192; pB += 8192;
        __syncthreads();

#pragma unroll
        for (int s = 0; s < 2; ++s) {
            f16x8 af[4], bf[4];
            const int sb = s * 4096;
#pragma unroll
            for (int i = 0; i < 4; ++i)
                af[i] = *(const f16x8*)(As + sb + (size_t)((kq + wm + i * 16 + l15) << 3));
#pragma unroll
            for (int j = 0; j < 4; ++j)
                bf[j] = *(const f16x8*)(Bs + sb + (size_t)((kq + wn + j * 16 + l15) << 3));
#pragma unroll
            for (int i = 0; i < 4; ++i)
#pragma unroll
                for (int j = 0; j < 4; ++j)
                    acc[i][j] = __builtin_amdgcn_mfma_f32_16x16x32_f16(af[i], bf[j], acc[i][j], 0, 0, 0);
        }
    }
    // leftover: BK=32
    if (kt < KT) {
        __syncthreads();
        gld_lds16(pA + (size_t)(cb0 + lane) * 8, As + cb0 * 8);
        gld_lds16(pA + (size_t)(cb1 + lane) * 8, As + cb1 * 8);
        gld_lds16(pB + (size_t)(cb0 + lane) * 8, Bs + cb0 * 8);
        gld_lds16(pB + (size_t)(cb1 + lane) * 8, Bs + cb1 * 8);
        __syncthreads();
        f16x8 af[4], bf[4];
#pragma unroll
        for (int i = 0; i < 4; ++i)
            af[i] = *(const f16x8*)(As + (size_t)((kq + wm + i * 16 + l15) << 3));
#pragma unroll
        for (int j = 0; j < 4; ++j)
            bf[j] = *(const f16x8*)(Bs + (size_t)((kq + wn + j * 16 + l15) << 3));
#pragma unroll
        for (int i = 0; i < 4; ++i)
#pragma unroll
            for (int j = 0; j < 4; ++j)
                acc[i][j] = __builtin_amdgcn_mfma_f32_16x16x32_f16(af[i], bf[j], acc[i][j], 0, 0, 0);
    }

    if (MODE == 0) {
        // re-block C through LDS, two passes of 64 rows (tr = [64][132] f16)
        _Float16* tr = (_Float16*)smem;
#pragma unroll
        for (int pass = 0; pass < 2; ++pass) {
            __syncthreads();
            if (wm == pass * 64) {
#pragma unroll
                for (int i = 0; i < 4; ++i) {
#pragma unroll
                    for (int v = 0; v < 4; ++v) {
                        const int lr = i * 16 + l4 + v;
                        const float* brow = bias;
                        if (gbid) {
                            int m = p * 128 + pass * 64 + lr;
                            if (m >= M) m = M - 1;
                            brow = bias + (size_t)clampi(gbid[m], BB) * ldbias;
                        }
#pragma unroll
                        for (int j = 0; j < 4; ++j) {
                            const int cc = wn + j * 16 + l15;
                            float val = acc[i][j][v] + brow[c * 128 + cc];
                            if (relu) val = fmaxf(val, 0.f);
                            tr[lr * 132 + cc] = (_Float16)val;
                        }
                    }
                }
            }
            __syncthreads();
#pragma unroll
            for (int it = 0; it < 4; ++it) {
                const int id = it * 256 + tid;
                const int r  = id & 63;
                const int cg = id >> 6;
                f16x4 lo = *(const f16x4*)(tr + r * 132 + cg * 8);
                f16x4 hi = *(const f16x4*)(tr + r * 132 + cg * 8 + 4);
                f16x8 v8;
#pragma unroll
                for (int t = 0; t < 4; ++t) { v8[t] = lo[t]; v8[t + 4] = hi[t]; }
                const int kti = ktOff + (c << 2) + (cg >> 2);
                const int gr  = pass * 64 + r;
                size_t o = (((size_t)p * KTo + kti) * 4 + (cg & 3)) * 1024 + (size_t)gr * 8;
                *(f16x8*)((_Float16*)C + o) = v8;
            }
        }
    } else if (MODE == 1) {
#pragma unroll
        for (int i = 0; i < 4; ++i) {
#pragma unroll
            for (int v = 0; v < 4; ++v) {
                const int m = p * 128 + wm + i * 16 + l4 + v;
                if (m >= M) continue;
                const float* brow = bias;
                if (gbid) brow = bias + (size_t)clampi(gbid[m], BB) * ldbias;
#pragma unroll
                for (int j = 0; j < 4; ++j) {
                    const int col = c * 128 + wn + j * 16 + l15;
                    float val = acc[i][j][v] + brow[col];
                    if (relu) val = fmaxf(val, 0.f);
                    ((float*)C)[(size_t)m * ldc + col] = val;
                }
            }
        }
    } else if (MODE == 2) {
        // fused coalesced scatter-add. 4 passes of 32 rows.
        float* trf = (float*)smem;   // [32][130] f32, 16640 B
#pragma unroll
        for (int pass = 0; pass < 4; ++pass) {
            __syncthreads();
            if (wm == ((pass >> 1) << 6)) {
                const int i0 = (pass & 1) << 1;
#pragma unroll
                for (int ii = 0; ii < 2; ++ii) {
                    const int i = i0 + ii;
                    const int lr = ii * 16 + l4;
#pragma unroll
                    for (int v = 0; v < 4; ++v) {
#pragma unroll
                        for (int j = 0; j < 4; ++j) {
                            const int cc = wn + j * 16 + l15;
                            float val = acc[i][j][v] + bias[c * 128 + cc];
                            if (relu) val = fmaxf(val, 0.f);
                            trf[(lr + v) * 130 + cc] = val;
                        }
                    }
                }
            }
            __syncthreads();
            const int ebase = p * 128 + pass * 32;
#pragma unroll
            for (int it = 0; it < 16; ++it) {
                const int id = it * 256 + tid;
                const int lr = id >> 7;
                const int colg = id & 127;
                const int el = ebase + lr;
                if (el < M) {
                    const int node = clampi(srow[el], NN);
                    atomicAdd(&aux[(size_t)node * 512 + c * 128 + colg],
                              trf[lr * 130 + colg]);
                }
            }
        }
    } else {
        // MODE 3: fused final dot. out[m] += sum_col relu(acc+bias[col])*mw1[col]
        // 16 lanes (l15) share each row -> shfl-reduce width 16, one atomic/row.
        const float* mw1 = aux;
        float* out = (float*)C;
#pragma unroll
        for (int i = 0; i < 4; ++i) {
#pragma unroll
            for (int v = 0; v < 4; ++v) {
                const int m = p * 128 + wm + i * 16 + l4 + v;
                const int mc = m < M ? m : M - 1;
                const float* brow = bias + (size_t)clampi(gbid[mc], BB) * ldbias;
                float s = 0.f;
#pragma unroll
                for (int j = 0; j < 4; ++j) {
                    const int col = c * 128 + wn + j * 16 + l15;
                    float val = acc[i][j][v] + brow[col];
                    val = fmaxf(val, 0.f);
                    s += val * mw1[col];
                }
                s += __shfl_down(s, 8, 16);
                s += __shfl_down(s, 4, 16);
                s += __shfl_down(s, 2, 16);
                s += __shfl_down(s, 1, 16);
                if (l15 == 0 && m < M) atomicAdd(&out[m], s);
            }
        }
    }
}

// ------------------------- helper kernels ----------------------------------

// fp32 -> blocked f16 [N/128][Kd/32].
// mode 0: plain; 1: e0 (k<19); 2: pack544; 4: transpose; 5: tail512
__global__ void k_w2h_blk(const float* __restrict__ src, _Float16* __restrict__ dst,
                          int N, int Ksrc, int Kd, int mode)
{
    int t = blockIdx.x * blockDim.x + threadIdx.x;
    if (t >= N * Kd) return;
    int n = t / Kd, k = t - n * Kd;
    float v = 0.f;
    if (mode == 0)      { if (k < Ksrc) v = src[(size_t)n * Ksrc + k]; }
    else if (mode == 1) { if (k < 19) v = src[(size_t)n * 275 + k]; }
    else if (mode == 2) { if (k < 9) v = src[(size_t)n * Ksrc + k];
                          else if (k >= 32 && k < 544) v = src[(size_t)n * Ksrc + 9 + (k - 32)]; }
    else if (mode == 4) { if (k < Ksrc) v = src[(size_t)k * N + n]; }
    else                { v = src[(size_t)n * Ksrc + 9 + k]; }
    int KT = Kd >> 5;
    int nt = n >> 7, r = n & 127, kt = k >> 5, kg = (k >> 3) & 3, ko = k & 7;
    dst[(((size_t)nt * KT + kt) * 4 + kg) * 1024 + (size_t)r * 8 + ko] = (_Float16)v;
}

// whnc kt32 slot: k' 0..31, value = nw0[n][k'] for k'<9 else 0
__global__ void k_fill_w32(const float* __restrict__ nw0, _Float16* __restrict__ whnc)
{
    int t = blockIdx.x * blockDim.x + threadIdx.x;
    if (t >= 512 * 32) return;
    int n = t >> 5, k = t & 31;
    float v = (k < 9) ? nw0[(size_t)n * 521 + k] : 0.f;
    int nt = n >> 7, r = n & 127, kg = (k >> 3) & 3, ko = k & 7;
    whnc[(((size_t)nt * 33 + 32) * 4 + kg) * 1024 + (size_t)r * 8 + ko] = (_Float16)v;
}

// bfused[n] = dot(nw0[n][9:521], eb4) + nb0[n]; one wave per n
__global__ void k_bfuse(const float* __restrict__ nw0, const float* __restrict__ eb4,
                        const float* __restrict__ nb0, float* __restrict__ bf)
{
    int wave = (blockIdx.x * 256 + threadIdx.x) >> 6;
    int lane = threadIdx.x & 63;
    if (wave >= 512) return;
    const float* wr = nw0 + (size_t)wave * 521 + 9;
    float s = 0.f;
#pragma unroll
    for (int i = 0; i < 8; ++i) s += wr[lane * 8 + i] * eb4[lane * 8 + i];
    for (int off = 32; off; off >>= 1) s += __shfl_down(s, off);
    if (lane == 0) bf[wave] = s + nb0[wave];
}

// u_r[16,256] fp32
__global__ void k_u_r(const float* __restrict__ u, const float* __restrict__ w_sel,
                      const float* __restrict__ b_sel, float* __restrict__ u_r)
{
    int wave = (blockIdx.x * 256 + threadIdx.x) >> 6;
    int lane = threadIdx.x & 63;
    int b = wave >> 8, n = wave & 255;
    const float4* u4 = (const float4*)(u + (size_t)b * 4096);
    const float4* w4 = (const float4*)(w_sel + (size_t)n * 4096);
    float s = 0.f;
    for (int i = lane; i < 1024; i += 64) {
        float4 a = u4[i], c = w4[i];
        s += a.x * c.x + a.y * c.y + a.z * c.z + a.w * c.w;
    }
    for (int off = 32; off; off >>= 1) s += __shfl_down(s, off);
    if (lane == 0) u_r[b * 256 + n] = s + b_sel[n];
}

// ub[16][Nout] = u_r @ w[:, koff:koff+256]^T + b
__global__ void k_graph_bias(const float* __restrict__ u_r, const float* __restrict__ w,
                             const float* __restrict__ b, float* __restrict__ ub,
                             int Nout, int Ksrc, int koff)
{
    int wave = (blockIdx.x * 256 + threadIdx.x) >> 6;
    int lane = threadIdx.x & 63;
    if (wave >= 16 * Nout) return;
    int g = wave / Nout, n = wave - g * Nout;
    const float* ur = u_r + (size_t)g * 256;
    const float* wr = w + (size_t)n * Ksrc + koff;
    float s = 0.f;
#pragma unroll
    for (int i = 0; i < 4; ++i) s += ur[lane * 4 + i] * wr[lane * 4 + i];
    for (int off = 32; off; off >>= 1) s += __shfl_down(s, off);
    if (lane == 0) ub[(size_t)g * Nout + n] = s + b[n];
}

// gbe + per-node edge count in one pass
__global__ void k_gbe(const int* __restrict__ row, const int* __restrict__ batch,
                      int* __restrict__ gbe, float* __restrict__ cnt)
{
    int e = blockIdx.x * blockDim.x + threadIdx.x;
    if (e >= EE) return;
    int r = clampi(row[e], NN);
    gbe[e] = clampi(batch[r], BB);
    atomicAdd(&cnt[r], 1.f);
}

// out[n] = mb1[0]  (atomic target init; d_out is poisoned pre-launch)
__global__ void k_init_out(float* __restrict__ out, const float* __restrict__ mb1)
{
    int t = blockIdx.x * blockDim.x + threadIdx.x;
    if (t < NN) out[t] = mb1[0];
}

// edge gather: e_in [MT][1] = [x[row](9)|x[col](9)|ea|0..]; ALSO writes
// x[col] into kt=32 slot of pong [MT][33] (used by nc GEMM).
__global__ void k_gather_edge_blk(const float* __restrict__ x, const float* __restrict__ ea,
                                  const int* __restrict__ row, const int* __restrict__ col,
                                  _Float16* __restrict__ dst, _Float16* __restrict__ pong,
                                  int e0, int ec, int MTR)
{
    int t = blockIdx.x * blockDim.x + threadIdx.x;
    if (t >= MTR * 4) return;
    int r = t >> 2, kg = t & 3;
    int e = e0 + r; int emax = e0 + ec - 1;
    if (e > emax) e = emax;
    int ri = clampi(row[e], NN), ci = clampi(col[e], NN);
    f16x8 v;
    f16x8 vx = (f16x8)(_Float16)0.f;
#pragma unroll
    for (int j = 0; j < 8; ++j) {
        int cc = kg * 8 + j;
        float fv = 0.f;
        if (cc < 9)       fv = x[(size_t)ri * 9 + cc];
        else if (cc < 18) fv = x[(size_t)ci * 9 + (cc - 9)];
        else if (cc == 18) fv = ea[e];
        v[j] = (_Float16)fv;
        if (cc < 9) vx[j] = (_Float16)x[(size_t)ci * 9 + cc];
    }
    *(f16x8*)(dst + (size_t)(r >> 7) * 4096 + (size_t)kg * 1024 + (size_t)(r & 127) * 8) = v;
    *(f16x8*)(pong + (((size_t)(r >> 7) * 33 + 32) * 4 + kg) * 1024 + (size_t)(r & 127) * 8) = vx;
}

// m_in blocked [MTm][17]: cols = [x(9)|pad23 | agg/cnt(512)]
__global__ void k_gather_min(const float* __restrict__ x, const float* __restrict__ agg,
                             const float* __restrict__ cnt, _Float16* __restrict__ dst, int MTR)
{
    int t = blockIdx.x * blockDim.x + threadIdx.x;
    if (t >= MTR * 68) return;
    int r = t / 68, q = t - r * 68;
    int kt = q >> 2, kg = q & 3;
    int n = r < NN ? r : NN - 1;
    f16x8 v = (f16x8)(_Float16)0.f;
    if (kt == 0) {
#pragma unroll
        for (int j = 0; j < 8; ++j) {
            int cc = kg * 8 + j;
            if (cc < 9) v[j] = (_Float16)x[(size_t)n * 9 + cc];
        }
    } else {
        float inv = 1.f / fmaxf(cnt[n], 1.f);
        int cbase = (kt - 1) * 32 + kg * 8;
        const float4* ap = (const float4*)(agg + (size_t)n * 512 + cbase);
        float4 a0 = ap[0], a1 = ap[1];
        v[0] = (_Float16)(a0.x * inv); v[1] = (_Float16)(a0.y * inv);
        v[2] = (_Float16)(a0.z * inv); v[3] = (_Float16)(a0.w * inv);
        v[4] = (_Float16)(a1.x * inv); v[5] = (_Float16)(a1.y * inv);
        v[6] = (_Float16)(a1.z * inv); v[7] = (_Float16)(a1.w * inv);
    }
    *(f16x8*)(dst + ((size_t)(r >> 7) * 17 + kt) * 4096 + (size_t)kg * 1024 + (size_t)(r & 127) * 8) = v;
}

// ------------------------------- host --------------------------------------

#define GRID1(n) dim3(((n) + 255) / 256)

static inline void gemmB0(hipStream_t s, const _Float16* A, const _Float16* Wt, int KT, int KTs,
                          const float* bias, int ldbias, const int* gbid,
                          void* C, int KTo, int ktOff,
                          int M, int MT, int NT, int relu)
{
    hipLaunchKernelGGL(gemm_blk<0>, dim3(NT, MT), dim3(256), 0, s,
                       A, Wt, KT, KTs, bias, ldbias, gbid, C, KTo, ktOff, 0,
                       nullptr, nullptr, M, relu);
}
static inline void gemmB2(hipStream_t s, const _Float16* A, const _Float16* Wt, int KT, int KTs,
                          const float* bias, const int* srow, float* agg,
                          int M, int MT, int NT, int relu)
{
    hipLaunchKernelGGL(gemm_blk<2>, dim3(NT, MT), dim3(256), 0, s,
                       A, Wt, KT, KTs, bias, 0, nullptr, nullptr, 0, 0, 0,
                       srow, agg, M, relu);
}
static inline void gemmB3(hipStream_t s, const _Float16* A, const _Float16* Wt, int KT, int KTs,
                          const float* bias, int ldbias, const int* gbid,
                          float* out, const float* mw1,
                          int M, int MT, int NT)
{
    hipLaunchKernelGGL(gemm_blk<3>, dim3(NT, MT), dim3(256), 0, s,
                       A, Wt, KT, KTs, bias, ldbias, gbid, out, 0, 0, 0,
                       nullptr, (float*)mw1, M, 1);
}

extern "C" void kernel_launch(void* const* d_in, const int* in_sizes, int n_in,
                              void* d_out, int out_size, void* d_ws, size_t ws_size,
                              hipStream_t stream)
{
    const float* x     = (const float*)d_in[0];
    const int*   ei    = (const int*)d_in[1];
    const float* ea    = (const float*)d_in[2];
    const float* u     = (const float*)d_in[3];
    const int*   batch = (const int*)d_in[4];
    const float* w_sel = (const float*)d_in[5];
    const float* b_sel = (const float*)d_in[6];
    const float* ew0 = (const float*)d_in[7];   const float* eb0 = (const float*)d_in[8];
    const float* ew1 = (const float*)d_in[9];   const float* eb1 = (const float*)d_in[10];
    const float* ew2 = (const float*)d_in[11];  const float* eb2 = (const float*)d_in[12];
    const float* ew3 = (const float*)d_in[13];  const float* eb3 = (const float*)d_in[14];
    const float* ew4 = (const float*)d_in[15];  const float* eb4 = (const float*)d_in[16];
    const float* nw0 = (const float*)d_in[17];  const float* nb0 = (const float*)d_in[18];
    const float* nw1 = (const float*)d_in[19];  const float* nb1 = (const float*)d_in[20];
    const float* mw0 = (const float*)d_in[21];  const float* mb0 = (const float*)d_in[22];
    const float* mw1 = (const float*)d_in[23];  const float* mb1 = (const float*)d_in[24];

    const int* row = ei;
    const int* col = ei + EE;

    char* W = (char*)d_ws;
    size_t off = 0;
    auto alloc = [&](size_t bytes) -> char* {
        char* p = W + off;
        off = (off + bytes + 255) & ~(size_t)255;
        return p;
    };
    float*    cnt   = (float*)alloc(20000 * 4);
    float*    agg   = (float*)alloc((size_t)NN * 512 * 4);
    float*    zbias = (float*)alloc(1024 * 4);          // stays zero (for W_comb GEMM)
    const size_t zeroBytes = off;
    float*    u_r  = (float*)alloc(16 * 256 * 4);
    float*    ub0  = (float*)alloc(16 * 1024 * 4);
    float*    ubm  = (float*)alloc(16 * 512 * 4);
    float*    bfu  = (float*)alloc(512 * 4);            // fused nc bias
    int*      gbe  = (int*)alloc((size_t)EE * 4);
    _Float16* wh0   = (_Float16*)alloc((size_t)8 * 1 * 4096 * 2);
    _Float16* wh1   = (_Float16*)alloc((size_t)8 * 32 * 4096 * 2);
    _Float16* wh2   = (_Float16*)alloc((size_t)8 * 32 * 4096 * 2);
    _Float16* wh3   = (_Float16*)alloc((size_t)8 * 32 * 4096 * 2);
    _Float16* whnc  = (_Float16*)alloc((size_t)4 * 33 * 4096 * 2);  // [W_comb | nw0_x]
    _Float16* whn1  = (_Float16*)alloc((size_t)4 * 16 * 4096 * 2);
    _Float16* whm0  = (_Float16*)alloc((size_t)4 * 17 * 4096 * 2);
    _Float16* nw0eoB= (_Float16*)alloc((size_t)4 * 16 * 4096 * 2);  // nw0[:,9:521] blocked
    _Float16* ew4T  = (_Float16*)alloc((size_t)8 * 16 * 4096 * 2);  // ew4^T blocked
    const int MTm = (NN + 127) / 128;           // 157
    _Float16* m_in = (_Float16*)alloc((size_t)MTm * 17 * 4096 * 2);
    const size_t fixedBytes = off;

    // choose edge chunk (depends only on ws_size -> capture-safe).
    static const int ecOpts[] = {50000, 25000, 12500, 10000, 5000};
    int EC = 5000;
    for (int i = 0; i < 5; ++i) {
        int ec = ecOpts[i];
        size_t MTRc = (size_t)((ec + 127) / 128) * 128;
        size_t need = fixedBytes + MTRc * 64 + 2 * (MTRc * 2112) + 4096;
        if (need <= ws_size) { EC = ec; break; }
    }
    const int MT  = (EC + 127) / 128;
    const size_t MTR = (size_t)MT * 128;
    _Float16* e_in = (_Float16*)alloc(MTR * 64);        // [MT][1]
    _Float16* ping = (_Float16*)alloc(MTR * 2112);      // [MT][33]
    _Float16* pong = (_Float16*)alloc(MTR * 2112);      // [MT][33]
    const int NCH = (EE + EC - 1) / EC;

    (void)hipMemsetAsync(W, 0, zeroBytes, stream);
    hipLaunchKernelGGL(k_init_out, GRID1(NN), dim3(256), 0, stream, (float*)d_out, mb1);

    hipLaunchKernelGGL(k_u_r, dim3(1024), dim3(256), 0, stream, u, w_sel, b_sel, u_r);
    hipLaunchKernelGGL(k_graph_bias, GRID1(16 * 1024 * 64), dim3(256), 0, stream,
                       u_r, ew0, eb0, ub0, 1024, 275, 19);
    hipLaunchKernelGGL(k_graph_bias, GRID1(16 * 512 * 64), dim3(256), 0, stream,
                       u_r, mw0, mb0, ubm, 512, 777, 521);
    hipLaunchKernelGGL(k_gbe, GRID1(EE), dim3(256), 0, stream, row, batch, gbe, cnt);
    hipLaunchKernelGGL(k_bfuse, dim3(128), dim3(256), 0, stream, nw0, eb4, nb0, bfu);

    auto pack = [&](const float* w, _Float16* wh, int N, int Ksrc, int Kd, int mode) {
        hipLaunchKernelGGL(k_w2h_blk, GRID1(N * Kd), dim3(256), 0, stream, w, wh, N, Ksrc, Kd, mode);
    };
    pack(ew0, wh0, 1024, 275, 32, 1);
    pack(ew1, wh1, 1024, 1024, 1024, 0);
    pack(ew2, wh2, 1024, 1024, 1024, 0);
    pack(ew3, wh3, 1024, 1024, 1024, 0);
    pack(nw1, whn1, 512, 512, 512, 0);
    pack(mw0, whm0, 512, 777, 544, 2);
    pack(nw0, nw0eoB, 512, 521, 512, 5);    // nw0[:,9:521]
    pack(ew4, ew4T, 1024, 512, 512, 4);     // ew4^T  (v = ew4[k][n])
    // W_comb = nw0eo @ ew4 : M=512, N=1024, K=512 -> whnc kt 0..31 (blocked out)
    gemmB0(stream, nw0eoB, ew4T, 16, 16, zbias, 0, nullptr, whnc, 33, 0, 512, 4, 8, 0);
    hipLaunchKernelGGL(k_fill_w32, GRID1(512 * 32), dim3(256), 0, stream, nw0, whnc);

    for (int ch = 0; ch < NCH; ++ch) {
        int e0 = ch * EC;
        int ec = EC; if (e0 + ec > EE) ec = EE - e0;
        // edge gather (also fills pong kt=32 with x[col] for the nc GEMM)
        hipLaunchKernelGGL(k_gather_edge_blk, GRID1((int)MTR * 4), dim3(256), 0, stream,
                           x, ea, row, col, e_in, pong, e0, ec, (int)MTR);
        // l0: K=32, per-graph bias ub0
        gemmB0(stream, e_in, wh0, 1, 1, ub0, 1024, gbe + e0, ping, 33, 0, ec, MT, 8, 1);
        gemmB0(stream, ping, wh1, 32, 33, eb1, 0, nullptr, pong, 33, 0, ec, MT, 8, 1);
        gemmB0(stream, pong, wh2, 32, 33, eb2, 0, nullptr, ping, 33, 0, ec, MT, 8, 1);
        gemmB0(stream, ping, wh3, 32, 33, eb3, 0, nullptr, pong, 33, 0, ec, MT, 8, 1);
        // nc: fused (ew4+nw0) GEMM, K=1056 (kt32 slot = x[col], pre-filled)
        gemmB0(stream, pong, whnc, 33, 33, bfu, 0, nullptr, ping, 16, 0, ec, MT, 4, 1);
        // n1: fused COALESCED scatter-add into agg (mode 2)
        gemmB2(stream, ping, whn1, 16, 16, nb1, row + e0, agg, ec, MT, 4, 1);
    }

    hipLaunchKernelGGL(k_gather_min, GRID1((int)(MTm * 128) * 68), dim3(256), 0, stream,
                       x, agg, cnt, m_in, MTm * 128);
    // m0 + final fused (mode 3): out[m] = mb1 + relu(m_in@mw0^T + ubm[batch]).mw1
    gemmB3(stream, m_in, whm0, 17, 17, ubm, 512, batch, (float*)d_out, mw1, NN, MTm, 4);
}